// Round 3
// baseline (438.630 us; speedup 1.0000x reference)
//
#include <hip/hip_runtime.h>

using u16 = unsigned short;
typedef __attribute__((ext_vector_type(4))) float f32x4;
typedef __attribute__((ext_vector_type(8))) short s16x8;

#define MFMA(a, b, c) __builtin_amdgcn_mfma_f32_16x16x32_bf16((a), (b), (c), 0, 0, 0)

__device__ __forceinline__ u16 f2bf(float f) {
  unsigned u = __float_as_uint(f);
  u += 0x7fff + ((u >> 16) & 1);
  return (u16)(u >> 16);
}
__device__ __forceinline__ float bf2f(u16 h) {
  return __uint_as_float((unsigned)h << 16);
}

// ---------------------------------------------------------------- transpose + bf16 convert (one matrix)
// src [K][N] fp32 -> dst [N][K] bf16 (hi); optional dstlo = bf16(x - hi).
__global__ __launch_bounds__(256) void tr_kernel(const float* src, u16* dst, u16* dstlo, int K, int N) {
  __shared__ float t[32][33];
  int ntn = N >> 5;
  int tk = blockIdx.x / ntn, tn = blockIdx.x - tk * ntn;
  int k0 = tk << 5, n0 = tn << 5;
  int r = threadIdx.x >> 3, c4 = (threadIdx.x & 7) << 2;
  const float* s = src + (size_t)(k0 + r) * N + n0 + c4;
  float4 v = *(const float4*)s;
  t[r][c4 + 0] = v.x;
  t[r][c4 + 1] = v.y;
  t[r][c4 + 2] = v.z;
  t[r][c4 + 3] = v.w;
  __syncthreads();
  size_t o = (size_t)(n0 + r) * K + k0 + c4;
#pragma unroll
  for (int j = 0; j < 4; j++) {
    float x = t[c4 + j][r];
    u16 hi = f2bf(x);
    dst[o + j] = hi;
    if (dstlo) dstlo[o + j] = f2bf(x - bf2f(hi));
  }
}

// ---------------------------------------------------------------- LayerNorm (W=256), one branch
__global__ __launch_bounds__(256) void ln1_kernel(const float* x, const float* g, const float* b, u16* out) {
  int lane = threadIdx.x & 63, wid = threadIdx.x >> 6;
  int row = blockIdx.x * 4 + wid;
  const float* xp = x + (size_t)row * 256;
  float v[4], s = 0.f, s2 = 0.f;
#pragma unroll
  for (int j = 0; j < 4; j++) {
    v[j] = xp[lane + 64 * j];
    s += v[j];
    s2 += v[j] * v[j];
  }
#pragma unroll
  for (int m = 32; m; m >>= 1) {
    s += __shfl_xor(s, m);
    s2 += __shfl_xor(s2, m);
  }
  float mean = s * (1.f / 256.f);
  float rstd = rsqrtf(s2 * (1.f / 256.f) - mean * mean + 1e-5f);
  u16* o = out + (size_t)row * 256;
#pragma unroll
  for (int j = 0; j < 4; j++) {
    int c = lane + 64 * j;
    o[c] = f2bf((v[j] - mean) * rstd * g[c] + b[c]);
  }
}

// ---------------------------------------------------------------- LayerNorm2 (W=768), split hi/lo out
__global__ __launch_bounds__(256) void ln2_kernel(const float* xc, const float* g, const float* b,
                                                  u16* oh, u16* ol) {
  int lane = threadIdx.x & 63, wid = threadIdx.x >> 6;
  int row = blockIdx.x * 4 + wid;
  float v[12], s = 0.f, s2 = 0.f;
#pragma unroll
  for (int j = 0; j < 12; j++) {
    int c = lane + 64 * j;
    v[j] = xc[(size_t)(c >> 8) * 1048576 + (size_t)row * 256 + (c & 255)];
    s += v[j];
    s2 += v[j] * v[j];
  }
#pragma unroll
  for (int m = 32; m; m >>= 1) {
    s += __shfl_xor(s, m);
    s2 += __shfl_xor(s2, m);
  }
  float mean = s * (1.f / 768.f);
  float rstd = rsqrtf(s2 * (1.f / 768.f) - mean * mean + 1e-5f);
#pragma unroll
  for (int j = 0; j < 12; j++) {
    int c = lane + 64 * j;
    float y = (v[j] - mean) * rstd * g[c] + b[c];
    u16 hi = f2bf(y);
    oh[(size_t)row * 768 + c] = hi;
    ol[(size_t)row * 768 + c] = f2bf(y - bf2f(hi));
  }
}

// ---------------------------------------------------------------- RMSNorm in-place, [4096][512], one branch
__global__ __launch_bounds__(256) void rms_kernel(u16* ao, const float* sc) {
  int lane = threadIdx.x & 63, wid = threadIdx.x >> 6;
  int row = blockIdx.x * 4 + wid;
  u16* p = ao + (size_t)row * 512;
  float v[8], s2 = 0.f;
#pragma unroll
  for (int j = 0; j < 8; j++) {
    v[j] = bf2f(p[lane + 64 * j]);
    s2 += v[j] * v[j];
  }
#pragma unroll
  for (int m = 32; m; m >>= 1) s2 += __shfl_xor(s2, m);
  float inv = 1.f / (sqrtf(s2) * 0.044194173824159216f + 1e-8f);  // *512^-0.5
#pragma unroll
  for (int j = 0; j < 8; j++) {
    int c = lane + 64 * j;
    p[c] = f2bf(v[j] * inv * sc[c]);
  }
}

// ---------------------------------------------------------------- GEMM 128x128 tile, bf16 MFMA (single)
// EPI 0: qkv scatter (+0.125 on q segment).  EPI 1: +bias+residual -> fp32 out.
struct GemmArgs {
  const u16* A;
  const u16* Bt;
  int K;
  const float* bias;
  const float* res;
  float* outf;
  u16 *q, *k, *v;
};

template <int EPI>
__global__ __launch_bounds__(256) void gemm_kernel(GemmArgs g) {
  __shared__ u16 As[128][40];
  __shared__ u16 Bs[128][40];
  const int tid = threadIdx.x;
  const int lane = tid & 63, wid = tid >> 6;
  const int wm = wid >> 1, wn = wid & 1;
  const int lr = lane & 15, lg = lane >> 4;
  const int m0 = blockIdx.y * 128, n0 = blockIdx.x * 128;
  const int K = g.K;
  f32x4 acc[4][4] = {};
  const int sr = tid >> 1, sh = (tid & 1) << 4;
  const u16* ga = g.A + (size_t)(m0 + sr) * K + sh;
  const u16* gb = g.Bt + (size_t)(n0 + sr) * K + sh;
  for (int k0 = 0; k0 < K; k0 += 32) {
    s16x8 a0 = *(const s16x8*)(ga + k0);
    s16x8 a1 = *(const s16x8*)(ga + k0 + 8);
    s16x8 b0 = *(const s16x8*)(gb + k0);
    s16x8 b1 = *(const s16x8*)(gb + k0 + 8);
    __syncthreads();
    *(s16x8*)&As[sr][sh] = a0;
    *(s16x8*)&As[sr][sh + 8] = a1;
    *(s16x8*)&Bs[sr][sh] = b0;
    *(s16x8*)&Bs[sr][sh + 8] = b1;
    __syncthreads();
    s16x8 af[4], bfr[4];
#pragma unroll
    for (int mt = 0; mt < 4; mt++) af[mt] = *(const s16x8*)&As[wm * 64 + mt * 16 + lr][lg * 8];
#pragma unroll
    for (int nt = 0; nt < 4; nt++) bfr[nt] = *(const s16x8*)&Bs[wn * 64 + nt * 16 + lr][lg * 8];
#pragma unroll
    for (int mt = 0; mt < 4; mt++)
#pragma unroll
      for (int nt = 0; nt < 4; nt++) acc[mt][nt] = MFMA(af[mt], bfr[nt], acc[mt][nt]);
  }
#pragma unroll
  for (int mt = 0; mt < 4; mt++) {
#pragma unroll
    for (int nt = 0; nt < 4; nt++) {
#pragma unroll
      for (int r = 0; r < 4; r++) {
        int row = m0 + wm * 64 + mt * 16 + lg * 4 + r;
        int col = n0 + wn * 64 + nt * 16 + lr;
        float val = acc[mt][nt][r];
        if (EPI == 0) {
          int seg = col >> 9, hh = (col >> 6) & 7, d = col & 63;
          u16* dst = seg == 0 ? g.q : (seg == 1 ? g.k : g.v);
          float scv = (seg == 0) ? 0.125f : 1.0f;
          int b = row >> 11, n = row & 2047;
          dst[(size_t)((b << 3) + hh) * 131072 + (size_t)n * 64 + d] = f2bf(val * scv);
        } else {
          val += g.bias[col] + g.res[(size_t)row * 256 + col];
          g.outf[(size_t)row * 256 + col] = val;
        }
      }
    }
  }
}

// ---------------------------------------------------------------- split-bf16 3-term GEMM (fp32-accurate)
struct Gemm3Args {
  const u16 *Ah, *Al, *Bh, *Bl;
  int K;
  const float* bias;
  u16 *oh, *ol;  // EPI 0
  float* outf;   // EPI 1 (RMW)
};

template <int EPI>
__global__ __launch_bounds__(256) void gemm3_kernel(Gemm3Args g) {
  __shared__ u16 Ahs[128][40], Als[128][40], Bhs[128][40], Bls[128][40];
  const int tid = threadIdx.x;
  const int lane = tid & 63, wid = tid >> 6;
  const int wm = wid >> 1, wn = wid & 1;
  const int lr = lane & 15, lg = lane >> 4;
  const int m0 = blockIdx.y * 128, n0 = blockIdx.x * 128;
  const int K = g.K;
  f32x4 acc[4][4] = {};
  const int sr = tid >> 1, sh = (tid & 1) << 4;
  const u16* gah = g.Ah + (size_t)(m0 + sr) * K + sh;
  const u16* gal = g.Al + (size_t)(m0 + sr) * K + sh;
  const u16* gbh = g.Bh + (size_t)(n0 + sr) * K + sh;
  const u16* gbl = g.Bl + (size_t)(n0 + sr) * K + sh;
  for (int k0 = 0; k0 < K; k0 += 32) {
    s16x8 ah0 = *(const s16x8*)(gah + k0);
    s16x8 ah1 = *(const s16x8*)(gah + k0 + 8);
    s16x8 al0 = *(const s16x8*)(gal + k0);
    s16x8 al1 = *(const s16x8*)(gal + k0 + 8);
    s16x8 bh0 = *(const s16x8*)(gbh + k0);
    s16x8 bh1 = *(const s16x8*)(gbh + k0 + 8);
    s16x8 bl0 = *(const s16x8*)(gbl + k0);
    s16x8 bl1 = *(const s16x8*)(gbl + k0 + 8);
    __syncthreads();
    *(s16x8*)&Ahs[sr][sh] = ah0;
    *(s16x8*)&Ahs[sr][sh + 8] = ah1;
    *(s16x8*)&Als[sr][sh] = al0;
    *(s16x8*)&Als[sr][sh + 8] = al1;
    *(s16x8*)&Bhs[sr][sh] = bh0;
    *(s16x8*)&Bhs[sr][sh + 8] = bh1;
    *(s16x8*)&Bls[sr][sh] = bl0;
    *(s16x8*)&Bls[sr][sh + 8] = bl1;
    __syncthreads();
    s16x8 fah[4], fal[4], fbh[4], fbl[4];
#pragma unroll
    for (int mt = 0; mt < 4; mt++) {
      fah[mt] = *(const s16x8*)&Ahs[wm * 64 + mt * 16 + lr][lg * 8];
      fal[mt] = *(const s16x8*)&Als[wm * 64 + mt * 16 + lr][lg * 8];
    }
#pragma unroll
    for (int nt = 0; nt < 4; nt++) {
      fbh[nt] = *(const s16x8*)&Bhs[wn * 64 + nt * 16 + lr][lg * 8];
      fbl[nt] = *(const s16x8*)&Bls[wn * 64 + nt * 16 + lr][lg * 8];
    }
#pragma unroll
    for (int mt = 0; mt < 4; mt++)
#pragma unroll
      for (int nt = 0; nt < 4; nt++) {
        acc[mt][nt] = MFMA(fah[mt], fbh[nt], acc[mt][nt]);
        acc[mt][nt] = MFMA(fah[mt], fbl[nt], acc[mt][nt]);
        acc[mt][nt] = MFMA(fal[mt], fbh[nt], acc[mt][nt]);
      }
  }
#pragma unroll
  for (int mt = 0; mt < 4; mt++) {
#pragma unroll
    for (int nt = 0; nt < 4; nt++) {
#pragma unroll
      for (int r = 0; r < 4; r++) {
        int row = m0 + wm * 64 + mt * 16 + lg * 4 + r;
        int col = n0 + wn * 64 + nt * 16 + lr;
        float val = acc[mt][nt][r] + g.bias[col];
        if (EPI == 0) {
          float ge = 0.5f * val * (1.0f + erff(val * 0.70710678118654752f));
          u16 hi = f2bf(ge);
          g.oh[(size_t)row * 1024 + col] = hi;
          g.ol[(size_t)row * 1024 + col] = f2bf(ge - bf2f(hi));
        } else {
          int chunk = col >> 8, cc = col & 255;
          float* p = g.outf + (size_t)chunk * 1048576 + (size_t)row * 256 + cc;
          *p = val + *p;
        }
      }
    }
  }
}

// ---------------------------------------------------------------- ReLU attention (one branch)
__global__ __launch_bounds__(256) void attn_kernel(const u16* q, const u16* k, const u16* v, u16* ao) {
  __shared__ u16 Ks[64][72];
  __shared__ u16 Vt[64][72];
  __shared__ u16 Ps[128][72];
  const int tid = threadIdx.x;
  const int lane = tid & 63, wid = tid >> 6;
  const int lr = lane & 15, lg = lane >> 4;
  const int qb = blockIdx.x, bh = blockIdx.y;
  const size_t boff = (size_t)bh * 131072;
  const u16* qp = q + boff;
  const u16* kp = k + boff;
  const u16* vp = v + boff;
  s16x8 qf[2][2];
#pragma unroll
  for (int mt = 0; mt < 2; mt++)
#pragma unroll
    for (int ks = 0; ks < 2; ks++)
      qf[mt][ks] = *(const s16x8*)(qp + (size_t)(qb * 128 + wid * 32 + mt * 16 + lr) * 64 + ks * 32 + lg * 8);
  f32x4 oacc[2][4] = {};
  const int sr = tid >> 2, sc = (tid & 3) << 4;
  const u16* kg = kp + sr * 64 + sc;
  const u16* vg = vp + sr * 64 + sc;
  for (int kt = 0; kt < 32; kt++) {
    s16x8 kv0 = *(const s16x8*)(kg + kt * 4096);
    s16x8 kv1 = *(const s16x8*)(kg + kt * 4096 + 8);
    s16x8 vv0 = *(const s16x8*)(vg + kt * 4096);
    s16x8 vv1 = *(const s16x8*)(vg + kt * 4096 + 8);
    __syncthreads();
    *(s16x8*)&Ks[sr][sc] = kv0;
    *(s16x8*)&Ks[sr][sc + 8] = kv1;
#pragma unroll
    for (int j = 0; j < 8; j++) {
      Vt[sc + j][sr] = (u16)vv0[j];
      Vt[sc + 8 + j][sr] = (u16)vv1[j];
    }
    __syncthreads();
    // S = Q K^T
    f32x4 sacc[2][4] = {};
#pragma unroll
    for (int nt = 0; nt < 4; nt++) {
#pragma unroll
      for (int ks = 0; ks < 2; ks++) {
        s16x8 kf = *(const s16x8*)&Ks[nt * 16 + lr][ks * 32 + lg * 8];
        sacc[0][nt] = MFMA(qf[0][ks], kf, sacc[0][nt]);
        sacc[1][nt] = MFMA(qf[1][ks], kf, sacc[1][nt]);
      }
    }
    // P = relu(S) -> LDS
#pragma unroll
    for (int mt = 0; mt < 2; mt++)
#pragma unroll
      for (int nt = 0; nt < 4; nt++)
#pragma unroll
        for (int r = 0; r < 4; r++) {
          float s = sacc[mt][nt][r];
          Ps[wid * 32 + mt * 16 + lg * 4 + r][nt * 16 + lr] = f2bf(s > 0.f ? s : 0.f);
        }
    __syncthreads();  // explicit barrier: P writes fully visible before PV reads
    // O += P V
#pragma unroll
    for (int ks = 0; ks < 2; ks++) {
      s16x8 pa0 = *(const s16x8*)&Ps[wid * 32 + lr][ks * 32 + lg * 8];
      s16x8 pa1 = *(const s16x8*)&Ps[wid * 32 + 16 + lr][ks * 32 + lg * 8];
#pragma unroll
      for (int nt = 0; nt < 4; nt++) {
        s16x8 vf = *(const s16x8*)&Vt[nt * 16 + lr][ks * 32 + lg * 8];
        oacc[0][nt] = MFMA(pa0, vf, oacc[0][nt]);
        oacc[1][nt] = MFMA(pa1, vf, oacc[1][nt]);
      }
    }
  }
  const int b = bh >> 3, h = bh & 7;
#pragma unroll
  for (int mt = 0; mt < 2; mt++)
#pragma unroll
    for (int nt = 0; nt < 4; nt++)
#pragma unroll
      for (int r = 0; r < 4; r++) {
        int qrow = qb * 128 + wid * 32 + mt * 16 + lg * 4 + r;
        ao[(size_t)(b * 2048 + qrow) * 512 + h * 64 + nt * 16 + lr] = f2bf(oacc[mt][nt][r]);
      }
}

// ----------------------------------------------------------------
extern "C" void kernel_launch(void* const* d_in, const int* in_sizes, int n_in,
                              void* d_out, int out_size, void* d_ws, size_t ws_size,
                              hipStream_t stream) {
  const float* X[3] = {(const float*)d_in[0], (const float*)d_in[1], (const float*)d_in[2]};
  const float* G1[3] = {(const float*)d_in[3], (const float*)d_in[9], (const float*)d_in[15]};
  const float* B1[3] = {(const float*)d_in[4], (const float*)d_in[10], (const float*)d_in[16]};
  const float* WQKV[3] = {(const float*)d_in[5], (const float*)d_in[11], (const float*)d_in[17]};
  const float* RMS[3] = {(const float*)d_in[6], (const float*)d_in[12], (const float*)d_in[18]};
  const float* WO[3] = {(const float*)d_in[7], (const float*)d_in[13], (const float*)d_in[19]};
  const float* BO[3] = {(const float*)d_in[8], (const float*)d_in[14], (const float*)d_in[20]};
  const float* G2 = (const float*)d_in[21];
  const float* B2 = (const float*)d_in[22];
  const float* WFC1 = (const float*)d_in[23];
  const float* BFC1 = (const float*)d_in[24];
  const float* WFC2 = (const float*)d_in[25];
  const float* BFC2 = (const float*)d_in[26];
  float* dout = (float*)d_out;

  // Compact workspace (u16 element offsets). Stage A (per-branch, reused) then
  // Stage B (MLP) overlapping dead Stage-A buffers. Peak = 17,825,792 elem = 34 MiB.
  u16* W = (u16*)d_ws;
  u16* wqkvT = W;               // [1536][256]   0 .. 393216
  u16* woT = W + 393216;        // [256][512]    .. 524288
  u16* xnz = W + 524288;        // [4096][256]   .. 1572864
  u16* qz = W + 1572864;        // [16][2048][64].. 3670016
  u16* kz = W + 3670016;        //               .. 5767168
  u16* vz = W + 5767168;        //               .. 7864320
  u16* aoz = W + 7864320;       // [4096][512]   .. 9961472
  // Stage B:
  u16* ln2h = W;                // [4096][768]   0 .. 3145728
  u16* ln2l = W + 3145728;      //               .. 6291456
  u16* fc1h = W + 6291456;      // [1024][768]   .. 7077888
  u16* fc1l = W + 7077888;      //               .. 7864320
  u16* fc2h = W + 7864320;      // [768][1024]   .. 8650752
  u16* fc2l = W + 8650752;      //               .. 9437184
  u16* hh = W + 9437184;        // [4096][1024]  .. 13631488
  u16* hl = W + 13631488;       //               .. 17825792

  // ---- Stage A: three branches sequentially
  for (int z = 0; z < 3; z++) {
    hipLaunchKernelGGL(tr_kernel, dim3(384), dim3(256), 0, stream,
                       WQKV[z], wqkvT, (u16*)nullptr, 256, 1536);
    hipLaunchKernelGGL(tr_kernel, dim3(128), dim3(256), 0, stream,
                       WO[z], woT, (u16*)nullptr, 512, 256);
    hipLaunchKernelGGL(ln1_kernel, dim3(1024), dim3(256), 0, stream, X[z], G1[z], B1[z], xnz);

    GemmArgs gq = {};
    gq.A = xnz;
    gq.Bt = wqkvT;
    gq.K = 256;
    gq.q = qz;
    gq.k = kz;
    gq.v = vz;
    hipLaunchKernelGGL(gemm_kernel<0>, dim3(12, 32), dim3(256), 0, stream, gq);

    hipLaunchKernelGGL(attn_kernel, dim3(16, 16), dim3(256), 0, stream, qz, kz, vz, aoz);
    hipLaunchKernelGGL(rms_kernel, dim3(1024), dim3(256), 0, stream, aoz, RMS[z]);

    GemmArgs gw = {};
    gw.A = aoz;
    gw.Bt = woT;
    gw.K = 512;
    gw.bias = BO[z];
    gw.res = X[z];
    gw.outf = dout + (size_t)z * 1048576;
    hipLaunchKernelGGL(gemm_kernel<1>, dim3(2, 32), dim3(256), 0, stream, gw);
  }

  // ---- Stage B: MLP (after all branches; Stage-A buffers dead)
  hipLaunchKernelGGL(tr_kernel, dim3(768), dim3(256), 0, stream, WFC1, fc1h, fc1l, 768, 1024);
  hipLaunchKernelGGL(tr_kernel, dim3(768), dim3(256), 0, stream, WFC2, fc2h, fc2l, 1024, 768);
  hipLaunchKernelGGL(ln2_kernel, dim3(1024), dim3(256), 0, stream, dout, G2, B2, ln2h, ln2l);

  Gemm3Args g1 = {};
  g1.Ah = ln2h;
  g1.Al = ln2l;
  g1.Bh = fc1h;
  g1.Bl = fc1l;
  g1.K = 768;
  g1.bias = BFC1;
  g1.oh = hh;
  g1.ol = hl;
  hipLaunchKernelGGL(gemm3_kernel<0>, dim3(8, 32), dim3(256), 0, stream, g1);

  Gemm3Args g2 = {};
  g2.Ah = hh;
  g2.Al = hl;
  g2.Bh = fc2h;
  g2.Bl = fc2l;
  g2.K = 1024;
  g2.bias = BFC2;
  g2.outf = dout;
  hipLaunchKernelGGL(gemm3_kernel<1>, dim3(6, 32), dim3(256), 0, stream, g2);
}

// Round 4
// 293.585 us; speedup vs baseline: 1.4940x; 1.4940x over previous
//
#include <hip/hip_runtime.h>

using u16 = unsigned short;
typedef __attribute__((ext_vector_type(4))) float f32x4;
typedef __attribute__((ext_vector_type(8))) short s16x8;

#define MFMA(a, b, c) __builtin_amdgcn_mfma_f32_16x16x32_bf16((a), (b), (c), 0, 0, 0)

__device__ __forceinline__ u16 f2bf(float f) {
  unsigned u = __float_as_uint(f);
  u += 0x7fff + ((u >> 16) & 1);
  return (u16)(u >> 16);
}
__device__ __forceinline__ float bf2f(u16 h) {
  return __uint_as_float((unsigned)h << 16);
}

// ---------------------------------------------------------------- transpose+convert all weights, one launch
struct TrArgs {
  const float* src[8];
  u16* dst[8];
  u16* dstlo[8];
  int K[8], N[8];
  int tstart[9];
};
__global__ __launch_bounds__(256) void tr_kernel(TrArgs a) {
  __shared__ float t[32][33];
  int tile = blockIdx.x;
  int m = 0;
  while (tile >= a.tstart[m + 1]) m++;
  int ti = tile - a.tstart[m];
  int K = a.K[m], N = a.N[m];
  int ntn = N >> 5;
  int tk = ti / ntn;
  int k0 = tk << 5, n0 = (ti - tk * ntn) << 5;
  int r = threadIdx.x >> 3, c4 = (threadIdx.x & 7) << 2;
  const float* s = a.src[m] + (size_t)(k0 + r) * N + n0 + c4;
  float4 v = *(const float4*)s;
  t[r][c4 + 0] = v.x;
  t[r][c4 + 1] = v.y;
  t[r][c4 + 2] = v.z;
  t[r][c4 + 3] = v.w;
  __syncthreads();
  size_t o = (size_t)(n0 + r) * K + k0 + c4;
  u16* d = a.dst[m];
  u16* dl = a.dstlo[m];
#pragma unroll
  for (int j = 0; j < 4; j++) {
    float x = t[c4 + j][r];
    u16 hi = f2bf(x);
    d[o + j] = hi;
    if (dl) dl[o + j] = f2bf(x - bf2f(hi));
  }
}

// ---------------------------------------------------------------- LayerNorm (W=256), batched over branches
struct LN1Args {
  const float* x[3];
  const float* g[3];
  const float* b[3];
  u16* out;  // [3][4096][256]
};
__global__ __launch_bounds__(256) void ln1_kernel(LN1Args a) {
  int lane = threadIdx.x & 63, wid = threadIdx.x >> 6;
  int row = blockIdx.x * 4 + wid;
  int br = blockIdx.y;
  const float* xp = a.x[br] + (size_t)row * 256;
  float v[4], s = 0.f, s2 = 0.f;
#pragma unroll
  for (int j = 0; j < 4; j++) {
    v[j] = xp[lane + 64 * j];
    s += v[j];
    s2 += v[j] * v[j];
  }
#pragma unroll
  for (int m = 32; m; m >>= 1) {
    s += __shfl_xor(s, m);
    s2 += __shfl_xor(s2, m);
  }
  float mean = s * (1.f / 256.f);
  float rstd = rsqrtf(s2 * (1.f / 256.f) - mean * mean + 1e-5f);
  u16* o = a.out + (size_t)br * 1048576 + (size_t)row * 256;
#pragma unroll
  for (int j = 0; j < 4; j++) {
    int c = lane + 64 * j;
    o[c] = f2bf((v[j] - mean) * rstd * a.g[br][c] + a.b[br][c]);
  }
}

// ---------------------------------------------------------------- LayerNorm2 (W=768), split hi/lo out
__global__ __launch_bounds__(256) void ln2_kernel(const float* xc, const float* g, const float* b,
                                                  u16* oh, u16* ol) {
  int lane = threadIdx.x & 63, wid = threadIdx.x >> 6;
  int row = blockIdx.x * 4 + wid;
  float v[12], s = 0.f, s2 = 0.f;
#pragma unroll
  for (int j = 0; j < 12; j++) {
    int c = lane + 64 * j;
    v[j] = xc[(size_t)(c >> 8) * 1048576 + (size_t)row * 256 + (c & 255)];
    s += v[j];
    s2 += v[j] * v[j];
  }
#pragma unroll
  for (int m = 32; m; m >>= 1) {
    s += __shfl_xor(s, m);
    s2 += __shfl_xor(s2, m);
  }
  float mean = s * (1.f / 768.f);
  float rstd = rsqrtf(s2 * (1.f / 768.f) - mean * mean + 1e-5f);
#pragma unroll
  for (int j = 0; j < 12; j++) {
    int c = lane + 64 * j;
    float y = (v[j] - mean) * rstd * g[c] + b[c];
    u16 hi = f2bf(y);
    oh[(size_t)row * 768 + c] = hi;
    ol[(size_t)row * 768 + c] = f2bf(y - bf2f(hi));
  }
}

// ---------------------------------------------------------------- sum 2 KV-split partials + RMSNorm -> aoN
__global__ __launch_bounds__(256) void rms_sum_kernel(const u16* ao4, const float* sc, u16* aoN) {
  int lane = threadIdx.x & 63, wid = threadIdx.x >> 6;
  int row = blockIdx.x * 4 + wid;
  const u16* p0 = ao4 + (size_t)row * 512;
  const u16* p1 = p0 + 2097152;
  float v[8], s2 = 0.f;
#pragma unroll
  for (int j = 0; j < 8; j++) {
    int c = lane + 64 * j;
    v[j] = bf2f(p0[c]) + bf2f(p1[c]);
    s2 += v[j] * v[j];
  }
#pragma unroll
  for (int m = 32; m; m >>= 1) s2 += __shfl_xor(s2, m);
  float inv = 1.f / (sqrtf(s2) * 0.044194173824159216f + 1e-8f);  // *512^-0.5
#pragma unroll
  for (int j = 0; j < 8; j++) {
    int c = lane + 64 * j;
    aoN[(size_t)row * 512 + c] = f2bf(v[j] * inv * sc[c]);
  }
}

// ---------------------------------------------------------------- QKV GEMM 128x128 (M=4096,N=1536,K=256)
struct GemmQkvArgs {
  const u16* A;
  const u16* Bt;
  u16 *q, *k, *v;
};
__global__ __launch_bounds__(256) void gemmqkv_kernel(GemmQkvArgs g) {
  __shared__ u16 As[128][40];
  __shared__ u16 Bs[128][40];
  const int tid = threadIdx.x;
  const int lane = tid & 63, wid = tid >> 6;
  const int wm = wid >> 1, wn = wid & 1;
  const int lr = lane & 15, lg = lane >> 4;
  const int m0 = blockIdx.y * 128, n0 = blockIdx.x * 128;
  const int K = 256;
  f32x4 acc[4][4] = {};
  const int sr = tid >> 1, sh = (tid & 1) << 4;
  const u16* ga = g.A + (size_t)(m0 + sr) * K + sh;
  const u16* gb = g.Bt + (size_t)(n0 + sr) * K + sh;
  for (int k0 = 0; k0 < K; k0 += 32) {
    s16x8 a0 = *(const s16x8*)(ga + k0);
    s16x8 a1 = *(const s16x8*)(ga + k0 + 8);
    s16x8 b0 = *(const s16x8*)(gb + k0);
    s16x8 b1 = *(const s16x8*)(gb + k0 + 8);
    __syncthreads();
    *(s16x8*)&As[sr][sh] = a0;
    *(s16x8*)&As[sr][sh + 8] = a1;
    *(s16x8*)&Bs[sr][sh] = b0;
    *(s16x8*)&Bs[sr][sh + 8] = b1;
    __syncthreads();
    s16x8 af[4], bfr[4];
#pragma unroll
    for (int mt = 0; mt < 4; mt++) af[mt] = *(const s16x8*)&As[wm * 64 + mt * 16 + lr][lg * 8];
#pragma unroll
    for (int nt = 0; nt < 4; nt++) bfr[nt] = *(const s16x8*)&Bs[wn * 64 + nt * 16 + lr][lg * 8];
#pragma unroll
    for (int mt = 0; mt < 4; mt++)
#pragma unroll
      for (int nt = 0; nt < 4; nt++) acc[mt][nt] = MFMA(af[mt], bfr[nt], acc[mt][nt]);
  }
#pragma unroll
  for (int mt = 0; mt < 4; mt++)
#pragma unroll
    for (int nt = 0; nt < 4; nt++)
#pragma unroll
      for (int r = 0; r < 4; r++) {
        int row = m0 + wm * 64 + mt * 16 + lg * 4 + r;
        int col = n0 + wn * 64 + nt * 16 + lr;
        float val = acc[mt][nt][r];
        int seg = col >> 9, hh = (col >> 6) & 7, d = col & 63;
        u16* dst = seg == 0 ? g.q : (seg == 1 ? g.k : g.v);
        float scv = (seg == 0) ? 0.125f : 1.0f;
        int b = row >> 11, n = row & 2047;
        dst[(size_t)((b << 3) + hh) * 131072 + (size_t)n * 64 + d] = f2bf(val * scv);
      }
}

// ---------------------------------------------------------------- WO GEMM 64x64 tile (+bias+residual->fp32)
struct Gemm64Args {
  const u16* A;   // [4096][512]
  const u16* Bt;  // [256][512]
  const float* bias;
  const float* res;
  float* outf;
};
__global__ __launch_bounds__(256) void gemm64_kernel(Gemm64Args g) {
  __shared__ u16 As[64][40];
  __shared__ u16 Bs[64][40];
  const int tid = threadIdx.x;
  const int lane = tid & 63, wid = tid >> 6;
  const int wm = wid >> 1, wn = wid & 1;
  const int lr = lane & 15, lg = lane >> 4;
  const int m0 = blockIdx.y * 64, n0 = blockIdx.x * 64;
  const int K = 512;
  f32x4 acc[2][2] = {};
  const int sr = tid >> 2, sh8 = (tid & 3) << 3;
  const u16* ga = g.A + (size_t)(m0 + sr) * K + sh8;
  const u16* gb = g.Bt + (size_t)(n0 + sr) * K + sh8;
  for (int k0 = 0; k0 < K; k0 += 32) {
    s16x8 a0 = *(const s16x8*)(ga + k0);
    s16x8 b0 = *(const s16x8*)(gb + k0);
    __syncthreads();
    *(s16x8*)&As[sr][sh8] = a0;
    *(s16x8*)&Bs[sr][sh8] = b0;
    __syncthreads();
    s16x8 af[2], bfr[2];
#pragma unroll
    for (int mt = 0; mt < 2; mt++) af[mt] = *(const s16x8*)&As[wm * 32 + mt * 16 + lr][lg * 8];
#pragma unroll
    for (int nt = 0; nt < 2; nt++) bfr[nt] = *(const s16x8*)&Bs[wn * 32 + nt * 16 + lr][lg * 8];
#pragma unroll
    for (int mt = 0; mt < 2; mt++)
#pragma unroll
      for (int nt = 0; nt < 2; nt++) acc[mt][nt] = MFMA(af[mt], bfr[nt], acc[mt][nt]);
  }
#pragma unroll
  for (int mt = 0; mt < 2; mt++)
#pragma unroll
    for (int nt = 0; nt < 2; nt++)
#pragma unroll
      for (int r = 0; r < 4; r++) {
        int row = m0 + wm * 32 + mt * 16 + lg * 4 + r;
        int col = n0 + wn * 32 + nt * 16 + lr;
        float val = acc[mt][nt][r] + g.bias[col] + g.res[(size_t)row * 256 + col];
        g.outf[(size_t)row * 256 + col] = val;
      }
}

// ---------------------------------------------------------------- split-bf16 3-term GEMM, 128x64 tile
struct Gemm3Args {
  const u16 *Ah, *Al, *Bh, *Bl;
  int K;
  const float* bias;
  u16 *oh, *ol;  // EPI 0 (gelu, N=1024)
  float* outf;   // EPI 1 (RMW d_out, N=768)
};
template <int EPI>
__global__ __launch_bounds__(256) void gemm3_kernel(Gemm3Args g) {
  __shared__ u16 Ahs[128][40], Als[128][40], Bhs[64][40], Bls[64][40];
  const int tid = threadIdx.x;
  const int lane = tid & 63, wid = tid >> 6;
  const int wm = wid >> 1, wn = wid & 1;
  const int lr = lane & 15, lg = lane >> 4;
  const int m0 = blockIdx.y * 128, n0 = blockIdx.x * 64;
  const int K = g.K;
  f32x4 acc[4][2] = {};
  const int sra = tid >> 1, sha = (tid & 1) << 4;
  const int srb = tid >> 2, shb = (tid & 3) << 3;
  const u16* gah = g.Ah + (size_t)(m0 + sra) * K + sha;
  const u16* gal = g.Al + (size_t)(m0 + sra) * K + sha;
  const u16* gbh = g.Bh + (size_t)(n0 + srb) * K + shb;
  const u16* gbl = g.Bl + (size_t)(n0 + srb) * K + shb;
  for (int k0 = 0; k0 < K; k0 += 32) {
    s16x8 ah0 = *(const s16x8*)(gah + k0);
    s16x8 ah1 = *(const s16x8*)(gah + k0 + 8);
    s16x8 al0 = *(const s16x8*)(gal + k0);
    s16x8 al1 = *(const s16x8*)(gal + k0 + 8);
    s16x8 bh0 = *(const s16x8*)(gbh + k0);
    s16x8 bl0 = *(const s16x8*)(gbl + k0);
    __syncthreads();
    *(s16x8*)&Ahs[sra][sha] = ah0;
    *(s16x8*)&Ahs[sra][sha + 8] = ah1;
    *(s16x8*)&Als[sra][sha] = al0;
    *(s16x8*)&Als[sra][sha + 8] = al1;
    *(s16x8*)&Bhs[srb][shb] = bh0;
    *(s16x8*)&Bls[srb][shb] = bl0;
    __syncthreads();
    s16x8 fah[4], fal[4], fbh[2], fbl[2];
#pragma unroll
    for (int mt = 0; mt < 4; mt++) {
      fah[mt] = *(const s16x8*)&Ahs[wm * 64 + mt * 16 + lr][lg * 8];
      fal[mt] = *(const s16x8*)&Als[wm * 64 + mt * 16 + lr][lg * 8];
    }
#pragma unroll
    for (int nt = 0; nt < 2; nt++) {
      fbh[nt] = *(const s16x8*)&Bhs[wn * 32 + nt * 16 + lr][lg * 8];
      fbl[nt] = *(const s16x8*)&Bls[wn * 32 + nt * 16 + lr][lg * 8];
    }
#pragma unroll
    for (int mt = 0; mt < 4; mt++)
#pragma unroll
      for (int nt = 0; nt < 2; nt++) {
        acc[mt][nt] = MFMA(fah[mt], fbh[nt], acc[mt][nt]);
        acc[mt][nt] = MFMA(fah[mt], fbl[nt], acc[mt][nt]);
        acc[mt][nt] = MFMA(fal[mt], fbh[nt], acc[mt][nt]);
      }
  }
#pragma unroll
  for (int mt = 0; mt < 4; mt++)
#pragma unroll
    for (int nt = 0; nt < 2; nt++)
#pragma unroll
      for (int r = 0; r < 4; r++) {
        int row = m0 + wm * 64 + mt * 16 + lg * 4 + r;
        int col = n0 + wn * 32 + nt * 16 + lr;
        float val = acc[mt][nt][r] + g.bias[col];
        if (EPI == 0) {
          float ge = 0.5f * val * (1.0f + erff(val * 0.70710678118654752f));
          u16 hi = f2bf(ge);
          g.oh[(size_t)row * 1024 + col] = hi;
          g.ol[(size_t)row * 1024 + col] = f2bf(ge - bf2f(hi));
        } else {
          int chunk = col >> 8, cc = col & 255;
          float* p = g.outf + (size_t)chunk * 1048576 + (size_t)row * 256 + cc;
          *p = val + *p;
        }
      }
}

// ---------------------------------------------------------------- ReLU attention, QBLK=64, KV-split=2
// grid (32, 16, 2). Partial O -> ao4[split][4096][512] bf16.
__global__ __launch_bounds__(256) void attn_kernel(const u16* q, const u16* k, const u16* v, u16* ao4) {
  __shared__ u16 Ks[64][72];
  __shared__ u16 Vt[64][72];  // [dh][kv], XOR-swizzled in 16B blocks
  __shared__ u16 Ps[64][72];
  const int tid = threadIdx.x;
  const int lane = tid & 63, wid = tid >> 6;
  const int lr = lane & 15, lg = lane >> 4;
  const int qb = blockIdx.x, bh = blockIdx.y, sp = blockIdx.z;
  const size_t boff = (size_t)bh * 131072;
  const u16* qp = q + boff;
  const u16* kp = k + boff;
  const u16* vp = v + boff;
  s16x8 qf[2];
#pragma unroll
  for (int ks = 0; ks < 2; ks++)
    qf[ks] = *(const s16x8*)(qp + (size_t)(qb * 64 + wid * 16 + lr) * 64 + ks * 32 + lg * 8);
  f32x4 oacc[4] = {};
  const int sr = tid >> 2, sc = (tid & 3) << 4;
  const u16* kg = kp + sr * 64 + sc;
  const u16* vg = vp + sr * 64 + sc;
  const int vb = sr >> 3, vw = sr & 7;  // 16B-block / within for Vt writes
  for (int kt = sp * 16; kt < sp * 16 + 16; kt++) {
    s16x8 kv0 = *(const s16x8*)(kg + kt * 4096);
    s16x8 kv1 = *(const s16x8*)(kg + kt * 4096 + 8);
    s16x8 vv0 = *(const s16x8*)(vg + kt * 4096);
    s16x8 vv1 = *(const s16x8*)(vg + kt * 4096 + 8);
    __syncthreads();  // prev tile's reads done
    *(s16x8*)&Ks[sr][sc] = kv0;
    *(s16x8*)&Ks[sr][sc + 8] = kv1;
#pragma unroll
    for (int j = 0; j < 8; j++) {
      int d0 = sc + j, d1 = sc + 8 + j;
      Vt[d0][(((vb ^ ((d0 >> 3) & 7)) << 3) | vw)] = (u16)vv0[j];
      Vt[d1][(((vb ^ ((d1 >> 3) & 7)) << 3) | vw)] = (u16)vv1[j];
    }
    __syncthreads();
    // S = Q K^T
    f32x4 sacc[4] = {};
#pragma unroll
    for (int nt = 0; nt < 4; nt++)
#pragma unroll
      for (int ks = 0; ks < 2; ks++) {
        s16x8 kf = *(const s16x8*)&Ks[nt * 16 + lr][ks * 32 + lg * 8];
        sacc[nt] = MFMA(qf[ks], kf, sacc[nt]);
      }
    // P = relu(S) -> LDS
#pragma unroll
    for (int nt = 0; nt < 4; nt++)
#pragma unroll
      for (int r = 0; r < 4; r++) {
        float s = sacc[nt][r];
        Ps[wid * 16 + lg * 4 + r][nt * 16 + lr] = f2bf(s > 0.f ? s : 0.f);
      }
    __syncthreads();
    // O += P V
#pragma unroll
    for (int ks = 0; ks < 2; ks++) {
      s16x8 pa = *(const s16x8*)&Ps[wid * 16 + lr][ks * 32 + lg * 8];
#pragma unroll
      for (int nt = 0; nt < 4; nt++) {
        int vrow = nt * 16 + lr;
        int pb = ((ks * 4 + lg) ^ ((vrow >> 3) & 7)) << 3;
        s16x8 vf = *(const s16x8*)&Vt[vrow][pb];
        oacc[nt] = MFMA(pa, vf, oacc[nt]);
      }
    }
  }
  const int b = bh >> 3, h = bh & 7;
#pragma unroll
  for (int nt = 0; nt < 4; nt++)
#pragma unroll
    for (int r = 0; r < 4; r++) {
      int qrow = qb * 64 + wid * 16 + lg * 4 + r;
      ao4[(size_t)sp * 2097152 + (size_t)(b * 2048 + qrow) * 512 + h * 64 + nt * 16 + lr] =
          f2bf(oacc[nt][r]);
    }
}

// ----------------------------------------------------------------
extern "C" void kernel_launch(void* const* d_in, const int* in_sizes, int n_in,
                              void* d_out, int out_size, void* d_ws, size_t ws_size,
                              hipStream_t stream) {
  const float* X[3] = {(const float*)d_in[0], (const float*)d_in[1], (const float*)d_in[2]};
  const float* G1[3] = {(const float*)d_in[3], (const float*)d_in[9], (const float*)d_in[15]};
  const float* B1[3] = {(const float*)d_in[4], (const float*)d_in[10], (const float*)d_in[16]};
  const float* WQKV[3] = {(const float*)d_in[5], (const float*)d_in[11], (const float*)d_in[17]};
  const float* RMS[3] = {(const float*)d_in[6], (const float*)d_in[12], (const float*)d_in[18]};
  const float* WO[3] = {(const float*)d_in[7], (const float*)d_in[13], (const float*)d_in[19]};
  const float* BO[3] = {(const float*)d_in[8], (const float*)d_in[14], (const float*)d_in[20]};
  const float* G2 = (const float*)d_in[21];
  const float* B2 = (const float*)d_in[22];
  const float* WFC1 = (const float*)d_in[23];
  const float* BFC1 = (const float*)d_in[24];
  const float* WFC2 = (const float*)d_in[25];
  const float* BFC2 = (const float*)d_in[26];
  float* dout = (float*)d_out;

  // Workspace layout (u16 element offsets). Peak 22,544,384 elem = 43 MiB.
  u16* W = (u16*)d_ws;
  u16* wqkvT = W;                  // [3][1536][256]  0 .. 1,179,648
  u16* woT = W + 1179648;          // [3][256][512]   .. 1,572,864
  u16* fc1h = W + 1572864;         // [1024][768]     .. 2,359,296
  u16* fc1l = W + 2359296;         //                 .. 3,145,728
  u16* fc2h = W + 3145728;         // [768][1024]     .. 3,932,160
  u16* fc2l = W + 3932160;         //                 .. 4,718,592
  u16* xn = W + 4718592;           // [3][4096][256]  .. 7,864,320
  u16* qz = W + 7864320;           // [16][2048][64]  .. 9,961,472   (per-branch reuse)
  u16* kz = W + 9961472;           //                 .. 12,058,624
  u16* vz = W + 12058624;          //                 .. 14,155,776
  u16* ao4 = W + 14155776;         // [2][4096][512]  .. 18,350,080
  u16* aoN = W + 18350080;         // [4096][512]     .. 20,447,232
  // Stage B overlays (stage-A buffers dead):
  u16* ln2h = W + 7864320;         // [4096][768]     .. 11,010,048
  u16* ln2l = W + 11010048;        //                 .. 14,155,776
  u16* hh = W + 14155776;          // [4096][1024]    .. 18,350,080
  u16* hl = W + 18350080;          //                 .. 22,544,384

  // 1) all weight transposes, one launch
  TrArgs ta;
  const float* srcs[8] = {WQKV[0], WQKV[1], WQKV[2], WO[0], WO[1], WO[2], WFC1, WFC2};
  u16* dsts[8] = {wqkvT, wqkvT + 393216, wqkvT + 786432, woT, woT + 131072, woT + 262144, fc1h, fc2h};
  u16* dlos[8] = {nullptr, nullptr, nullptr, nullptr, nullptr, nullptr, fc1l, fc2l};
  int Ks_[8] = {256, 256, 256, 512, 512, 512, 768, 1024};
  int Ns_[8] = {1536, 1536, 1536, 256, 256, 256, 1024, 768};
  int tst[9] = {0, 384, 768, 1152, 1280, 1408, 1536, 2304, 3072};
  for (int i = 0; i < 8; i++) {
    ta.src[i] = srcs[i];
    ta.dst[i] = dsts[i];
    ta.dstlo[i] = dlos[i];
    ta.K[i] = Ks_[i];
    ta.N[i] = Ns_[i];
    ta.tstart[i] = tst[i];
  }
  ta.tstart[8] = tst[8];
  hipLaunchKernelGGL(tr_kernel, dim3(3072), dim3(256), 0, stream, ta);

  // 2) LN1 batched
  LN1Args la;
  for (int i = 0; i < 3; i++) {
    la.x[i] = X[i];
    la.g[i] = G1[i];
    la.b[i] = B1[i];
  }
  la.out = xn;
  hipLaunchKernelGGL(ln1_kernel, dim3(1024, 3), dim3(256), 0, stream, la);

  // 3) per-branch pipeline
  for (int z = 0; z < 3; z++) {
    GemmQkvArgs gq = {xn + (size_t)z * 1048576, wqkvT + (size_t)z * 393216, qz, kz, vz};
    hipLaunchKernelGGL(gemmqkv_kernel, dim3(12, 32), dim3(256), 0, stream, gq);

    hipLaunchKernelGGL(attn_kernel, dim3(32, 16, 2), dim3(256), 0, stream, qz, kz, vz, ao4);

    hipLaunchKernelGGL(rms_sum_kernel, dim3(1024), dim3(256), 0, stream, ao4, RMS[z], aoN);

    Gemm64Args gw = {aoN, woT + (size_t)z * 131072, BO[z], X[z], dout + (size_t)z * 1048576};
    hipLaunchKernelGGL(gemm64_kernel, dim3(4, 64), dim3(256), 0, stream, gw);
  }

  // 4) LN2 -> hi/lo
  hipLaunchKernelGGL(ln2_kernel, dim3(1024), dim3(256), 0, stream, dout, G2, B2, ln2h, ln2l);

  // 5) FC1 (M=4096,N=1024,K=768) + gelu -> h hi/lo
  Gemm3Args g1 = {};
  g1.Ah = ln2h;
  g1.Al = ln2l;
  g1.Bh = fc1h;
  g1.Bl = fc1l;
  g1.K = 768;
  g1.bias = BFC1;
  g1.oh = hh;
  g1.ol = hl;
  hipLaunchKernelGGL(gemm3_kernel<0>, dim3(16, 32), dim3(256), 0, stream, g1);

  // 6) FC2 (M=4096,N=768,K=1024) + bias + residual RMW on d_out
  Gemm3Args g2 = {};
  g2.Ah = hh;
  g2.Al = hl;
  g2.Bh = fc2h;
  g2.Bl = fc2l;
  g2.K = 1024;
  g2.bias = BFC2;
  g2.outf = dout;
  hipLaunchKernelGGL(gemm3_kernel<1>, dim3(12, 32), dim3(256), 0, stream, g2);
}

// Round 5
// 260.959 us; speedup vs baseline: 1.6808x; 1.1250x over previous
//
#include <hip/hip_runtime.h>

using u16 = unsigned short;
typedef __attribute__((ext_vector_type(4))) float f32x4;
typedef __attribute__((ext_vector_type(8))) short s16x8;

#define MFMA(a, b, c) __builtin_amdgcn_mfma_f32_16x16x32_bf16((a), (b), (c), 0, 0, 0)

__device__ __forceinline__ u16 f2bf(float f) {
  unsigned u = __float_as_uint(f);
  u += 0x7fff + ((u >> 16) & 1);
  return (u16)(u >> 16);
}
__device__ __forceinline__ float bf2f(u16 h) {
  return __uint_as_float((unsigned)h << 16);
}

// ---------------------------------------------------------------- transpose+convert all weights, one launch
struct TrArgs {
  const float* src[8];
  u16* dst[8];
  int K[8], N[8];
  int tstart[9];
};
__global__ __launch_bounds__(256) void tr_kernel(TrArgs a) {
  __shared__ float t[32][33];
  int tile = blockIdx.x;
  int m = 0;
  while (tile >= a.tstart[m + 1]) m++;
  int ti = tile - a.tstart[m];
  int K = a.K[m], N = a.N[m];
  int ntn = N >> 5;
  int tk = ti / ntn;
  int k0 = tk << 5, n0 = (ti - tk * ntn) << 5;
  int r = threadIdx.x >> 3, c4 = (threadIdx.x & 7) << 2;
  const float* s = a.src[m] + (size_t)(k0 + r) * N + n0 + c4;
  float4 v = *(const float4*)s;
  t[r][c4 + 0] = v.x;
  t[r][c4 + 1] = v.y;
  t[r][c4 + 2] = v.z;
  t[r][c4 + 3] = v.w;
  __syncthreads();
  size_t o = (size_t)(n0 + r) * K + k0 + c4;
  u16* d = a.dst[m];
#pragma unroll
  for (int j = 0; j < 4; j++) d[o + j] = f2bf(t[c4 + j][r]);
}

// ---------------------------------------------------------------- LayerNorm (W=256), batched over branches
struct LN1Args {
  const float* x[3];
  const float* g[3];
  const float* b[3];
  u16* out;  // [3][4096][256]
};
__global__ __launch_bounds__(256) void ln1_kernel(LN1Args a) {
  int lane = threadIdx.x & 63, wid = threadIdx.x >> 6;
  int row = blockIdx.x * 4 + wid;
  int br = blockIdx.y;
  const float* xp = a.x[br] + (size_t)row * 256;
  float v[4], s = 0.f, s2 = 0.f;
#pragma unroll
  for (int j = 0; j < 4; j++) {
    v[j] = xp[lane + 64 * j];
    s += v[j];
    s2 += v[j] * v[j];
  }
#pragma unroll
  for (int m = 32; m; m >>= 1) {
    s += __shfl_xor(s, m);
    s2 += __shfl_xor(s2, m);
  }
  float mean = s * (1.f / 256.f);
  float rstd = rsqrtf(s2 * (1.f / 256.f) - mean * mean + 1e-5f);
  u16* o = a.out + (size_t)br * 1048576 + (size_t)row * 256;
#pragma unroll
  for (int j = 0; j < 4; j++) {
    int c = lane + 64 * j;
    o[c] = f2bf((v[j] - mean) * rstd * a.g[br][c] + a.b[br][c]);
  }
}

// ---------------------------------------------------------------- LayerNorm2 (W=768) -> bf16
__global__ __launch_bounds__(256) void ln2_kernel(const float* xc, const float* g, const float* b,
                                                  u16* oh) {
  int lane = threadIdx.x & 63, wid = threadIdx.x >> 6;
  int row = blockIdx.x * 4 + wid;
  float v[12], s = 0.f, s2 = 0.f;
#pragma unroll
  for (int j = 0; j < 12; j++) {
    int c = lane + 64 * j;
    v[j] = xc[(size_t)(c >> 8) * 1048576 + (size_t)row * 256 + (c & 255)];
    s += v[j];
    s2 += v[j] * v[j];
  }
#pragma unroll
  for (int m = 32; m; m >>= 1) {
    s += __shfl_xor(s, m);
    s2 += __shfl_xor(s2, m);
  }
  float mean = s * (1.f / 768.f);
  float rstd = rsqrtf(s2 * (1.f / 768.f) - mean * mean + 1e-5f);
#pragma unroll
  for (int j = 0; j < 12; j++) {
    int c = lane + 64 * j;
    oh[(size_t)row * 768 + c] = f2bf((v[j] - mean) * rstd * g[c] + b[c]);
  }
}

// ---------------------------------------------------------------- sum 2 KV-split partials + RMSNorm -> aoN
__global__ __launch_bounds__(256) void rms_sum_kernel(const u16* ao4, const float* sc, u16* aoN) {
  int lane = threadIdx.x & 63, wid = threadIdx.x >> 6;
  int row = blockIdx.x * 4 + wid;
  const u16* p0 = ao4 + (size_t)row * 512;
  const u16* p1 = p0 + 2097152;
  float v[8], s2 = 0.f;
#pragma unroll
  for (int j = 0; j < 8; j++) {
    int c = lane + 64 * j;
    v[j] = bf2f(p0[c]) + bf2f(p1[c]);
    s2 += v[j] * v[j];
  }
#pragma unroll
  for (int m = 32; m; m >>= 1) s2 += __shfl_xor(s2, m);
  float inv = 1.f / (sqrtf(s2) * 0.044194173824159216f + 1e-8f);  // *512^-0.5
#pragma unroll
  for (int j = 0; j < 8; j++) {
    int c = lane + 64 * j;
    aoN[(size_t)row * 512 + c] = f2bf(v[j] * inv * sc[c]);
  }
}

// ---------------------------------------------------------------- QKV GEMM 128x128 (M=4096,N=1536,K=256)
struct GemmQkvArgs {
  const u16* A;
  const u16* Bt;
  u16 *q, *k, *v;
};
__global__ __launch_bounds__(256) void gemmqkv_kernel(GemmQkvArgs g) {
  __shared__ u16 As[128][40];
  __shared__ u16 Bs[128][40];
  const int tid = threadIdx.x;
  const int lane = tid & 63, wid = tid >> 6;
  const int wm = wid >> 1, wn = wid & 1;
  const int lr = lane & 15, lg = lane >> 4;
  const int m0 = blockIdx.y * 128, n0 = blockIdx.x * 128;
  const int K = 256;
  f32x4 acc[4][4] = {};
  const int sr = tid >> 1, sh = (tid & 1) << 4;
  const u16* ga = g.A + (size_t)(m0 + sr) * K + sh;
  const u16* gb = g.Bt + (size_t)(n0 + sr) * K + sh;
  for (int k0 = 0; k0 < K; k0 += 32) {
    s16x8 a0 = *(const s16x8*)(ga + k0);
    s16x8 a1 = *(const s16x8*)(ga + k0 + 8);
    s16x8 b0 = *(const s16x8*)(gb + k0);
    s16x8 b1 = *(const s16x8*)(gb + k0 + 8);
    __syncthreads();
    *(s16x8*)&As[sr][sh] = a0;
    *(s16x8*)&As[sr][sh + 8] = a1;
    *(s16x8*)&Bs[sr][sh] = b0;
    *(s16x8*)&Bs[sr][sh + 8] = b1;
    __syncthreads();
    s16x8 af[4], bfr[4];
#pragma unroll
    for (int mt = 0; mt < 4; mt++) af[mt] = *(const s16x8*)&As[wm * 64 + mt * 16 + lr][lg * 8];
#pragma unroll
    for (int nt = 0; nt < 4; nt++) bfr[nt] = *(const s16x8*)&Bs[wn * 64 + nt * 16 + lr][lg * 8];
#pragma unroll
    for (int mt = 0; mt < 4; mt++)
#pragma unroll
      for (int nt = 0; nt < 4; nt++) acc[mt][nt] = MFMA(af[mt], bfr[nt], acc[mt][nt]);
  }
#pragma unroll
  for (int mt = 0; mt < 4; mt++)
#pragma unroll
    for (int nt = 0; nt < 4; nt++)
#pragma unroll
      for (int r = 0; r < 4; r++) {
        int row = m0 + wm * 64 + mt * 16 + lg * 4 + r;
        int col = n0 + wn * 64 + nt * 16 + lr;
        float val = acc[mt][nt][r];
        int seg = col >> 9, hh = (col >> 6) & 7, d = col & 63;
        u16* dst = seg == 0 ? g.q : (seg == 1 ? g.k : g.v);
        float scv = (seg == 0) ? 0.125f : 1.0f;
        int b = row >> 11, n = row & 2047;
        dst[(size_t)((b << 3) + hh) * 131072 + (size_t)n * 64 + d] = f2bf(val * scv);
      }
}

// ---------------------------------------------------------------- WO GEMM 64x64 tile (+bias+residual->fp32)
struct Gemm64Args {
  const u16* A;   // [4096][512]
  const u16* Bt;  // [256][512]
  const float* bias;
  const float* res;
  float* outf;
};
__global__ __launch_bounds__(256) void gemm64_kernel(Gemm64Args g) {
  __shared__ u16 As[64][40];
  __shared__ u16 Bs[64][40];
  const int tid = threadIdx.x;
  const int lane = tid & 63, wid = tid >> 6;
  const int wm = wid >> 1, wn = wid & 1;
  const int lr = lane & 15, lg = lane >> 4;
  const int m0 = blockIdx.y * 64, n0 = blockIdx.x * 64;
  const int K = 512;
  f32x4 acc[2][2] = {};
  const int sr = tid >> 2, sh8 = (tid & 3) << 3;
  const u16* ga = g.A + (size_t)(m0 + sr) * K + sh8;
  const u16* gb = g.Bt + (size_t)(n0 + sr) * K + sh8;
  for (int k0 = 0; k0 < K; k0 += 32) {
    s16x8 a0 = *(const s16x8*)(ga + k0);
    s16x8 b0 = *(const s16x8*)(gb + k0);
    __syncthreads();
    *(s16x8*)&As[sr][sh8] = a0;
    *(s16x8*)&Bs[sr][sh8] = b0;
    __syncthreads();
    s16x8 af[2], bfr[2];
#pragma unroll
    for (int mt = 0; mt < 2; mt++) af[mt] = *(const s16x8*)&As[wm * 32 + mt * 16 + lr][lg * 8];
#pragma unroll
    for (int nt = 0; nt < 2; nt++) bfr[nt] = *(const s16x8*)&Bs[wn * 32 + nt * 16 + lr][lg * 8];
#pragma unroll
    for (int mt = 0; mt < 2; mt++)
#pragma unroll
      for (int nt = 0; nt < 2; nt++) acc[mt][nt] = MFMA(af[mt], bfr[nt], acc[mt][nt]);
  }
#pragma unroll
  for (int mt = 0; mt < 2; mt++)
#pragma unroll
    for (int nt = 0; nt < 2; nt++)
#pragma unroll
      for (int r = 0; r < 4; r++) {
        int row = m0 + wm * 32 + mt * 16 + lg * 4 + r;
        int col = n0 + wn * 32 + nt * 16 + lr;
        float val = acc[mt][nt][r] + g.bias[col] + g.res[(size_t)row * 256 + col];
        g.outf[(size_t)row * 256 + col] = val;
      }
}

// ---------------------------------------------------------------- MLP GEMM, 128x64 tile, single bf16 term
// EPI 0: +bias, gelu -> bf16 (N=1024).  EPI 1: +bias + d_out residual RMW (N=768).
struct GemmMlpArgs {
  const u16 *A, *Bt;
  int K;
  const float* bias;
  u16* oh;      // EPI 0
  float* outf;  // EPI 1
};
template <int EPI>
__global__ __launch_bounds__(256) void gemmmlp_kernel(GemmMlpArgs g) {
  __shared__ u16 As[128][40], Bs[64][40];
  const int tid = threadIdx.x;
  const int lane = tid & 63, wid = tid >> 6;
  const int wm = wid >> 1, wn = wid & 1;
  const int lr = lane & 15, lg = lane >> 4;
  const int m0 = blockIdx.y * 128, n0 = blockIdx.x * 64;
  const int K = g.K;
  f32x4 acc[4][2] = {};
  const int sra = tid >> 1, sha = (tid & 1) << 4;
  const int srb = tid >> 2, shb = (tid & 3) << 3;
  const u16* ga = g.A + (size_t)(m0 + sra) * K + sha;
  const u16* gb = g.Bt + (size_t)(n0 + srb) * K + shb;
  for (int k0 = 0; k0 < K; k0 += 32) {
    s16x8 a0 = *(const s16x8*)(ga + k0);
    s16x8 a1 = *(const s16x8*)(ga + k0 + 8);
    s16x8 b0 = *(const s16x8*)(gb + k0);
    __syncthreads();
    *(s16x8*)&As[sra][sha] = a0;
    *(s16x8*)&As[sra][sha + 8] = a1;
    *(s16x8*)&Bs[srb][shb] = b0;
    __syncthreads();
    s16x8 af[4], bfr[2];
#pragma unroll
    for (int mt = 0; mt < 4; mt++) af[mt] = *(const s16x8*)&As[wm * 64 + mt * 16 + lr][lg * 8];
#pragma unroll
    for (int nt = 0; nt < 2; nt++) bfr[nt] = *(const s16x8*)&Bs[wn * 32 + nt * 16 + lr][lg * 8];
#pragma unroll
    for (int mt = 0; mt < 4; mt++)
#pragma unroll
      for (int nt = 0; nt < 2; nt++) acc[mt][nt] = MFMA(af[mt], bfr[nt], acc[mt][nt]);
  }
#pragma unroll
  for (int mt = 0; mt < 4; mt++)
#pragma unroll
    for (int nt = 0; nt < 2; nt++)
#pragma unroll
      for (int r = 0; r < 4; r++) {
        int row = m0 + wm * 64 + mt * 16 + lg * 4 + r;
        int col = n0 + wn * 32 + nt * 16 + lr;
        float val = acc[mt][nt][r] + g.bias[col];
        if (EPI == 0) {
          float ge = 0.5f * val * (1.0f + erff(val * 0.70710678118654752f));
          g.oh[(size_t)row * 1024 + col] = f2bf(ge);
        } else {
          int chunk = col >> 8, cc = col & 255;
          float* p = g.outf + (size_t)chunk * 1048576 + (size_t)row * 256 + cc;
          *p = val + *p;
        }
      }
}

// ---------------------------------------------------------------- ReLU attention, QBLK=64, KV-split=2
// grid (32, 16, 2). Partial O -> ao4[split][4096][512] bf16.
__global__ __launch_bounds__(256) void attn_kernel(const u16* q, const u16* k, const u16* v, u16* ao4) {
  __shared__ u16 Ks[64][72];
  __shared__ u16 Vt[64][72];  // [dh][kv], XOR-swizzled in 16B blocks
  __shared__ u16 Ps[64][72];
  const int tid = threadIdx.x;
  const int lane = tid & 63, wid = tid >> 6;
  const int lr = lane & 15, lg = lane >> 4;
  const int qb = blockIdx.x, bh = blockIdx.y, sp = blockIdx.z;
  const size_t boff = (size_t)bh * 131072;
  const u16* qp = q + boff;
  const u16* kp = k + boff;
  const u16* vp = v + boff;
  s16x8 qf[2];
#pragma unroll
  for (int ks = 0; ks < 2; ks++)
    qf[ks] = *(const s16x8*)(qp + (size_t)(qb * 64 + wid * 16 + lr) * 64 + ks * 32 + lg * 8);
  f32x4 oacc[4] = {};
  const int sr = tid >> 2, sc = (tid & 3) << 4;
  const u16* kg = kp + sr * 64 + sc;
  const u16* vg = vp + sr * 64 + sc;
  const int vb = sr >> 3, vw = sr & 7;  // 16B-block / within for Vt writes
  for (int kt = sp * 16; kt < sp * 16 + 16; kt++) {
    s16x8 kv0 = *(const s16x8*)(kg + kt * 4096);
    s16x8 kv1 = *(const s16x8*)(kg + kt * 4096 + 8);
    s16x8 vv0 = *(const s16x8*)(vg + kt * 4096);
    s16x8 vv1 = *(const s16x8*)(vg + kt * 4096 + 8);
    __syncthreads();  // prev tile's reads done
    *(s16x8*)&Ks[sr][sc] = kv0;
    *(s16x8*)&Ks[sr][sc + 8] = kv1;
#pragma unroll
    for (int j = 0; j < 8; j++) {
      int d0 = sc + j, d1 = sc + 8 + j;
      Vt[d0][(((vb ^ ((d0 >> 3) & 7)) << 3) | vw)] = (u16)vv0[j];
      Vt[d1][(((vb ^ ((d1 >> 3) & 7)) << 3) | vw)] = (u16)vv1[j];
    }
    __syncthreads();
    // S = Q K^T
    f32x4 sacc[4] = {};
#pragma unroll
    for (int nt = 0; nt < 4; nt++)
#pragma unroll
      for (int ks = 0; ks < 2; ks++) {
        s16x8 kf = *(const s16x8*)&Ks[nt * 16 + lr][ks * 32 + lg * 8];
        sacc[nt] = MFMA(qf[ks], kf, sacc[nt]);
      }
    // P = relu(S) -> LDS
#pragma unroll
    for (int nt = 0; nt < 4; nt++)
#pragma unroll
      for (int r = 0; r < 4; r++) {
        float s = sacc[nt][r];
        Ps[wid * 16 + lg * 4 + r][nt * 16 + lr] = f2bf(s > 0.f ? s : 0.f);
      }
    __syncthreads();
    // O += P V
#pragma unroll
    for (int ks = 0; ks < 2; ks++) {
      s16x8 pa = *(const s16x8*)&Ps[wid * 16 + lr][ks * 32 + lg * 8];
#pragma unroll
      for (int nt = 0; nt < 4; nt++) {
        int vrow = nt * 16 + lr;
        int pb = ((ks * 4 + lg) ^ ((vrow >> 3) & 7)) << 3;
        s16x8 vf = *(const s16x8*)&Vt[vrow][pb];
        oacc[nt] = MFMA(pa, vf, oacc[nt]);
      }
    }
  }
  const int b = bh >> 3, h = bh & 7;
#pragma unroll
  for (int nt = 0; nt < 4; nt++)
#pragma unroll
    for (int r = 0; r < 4; r++) {
      int qrow = qb * 64 + wid * 16 + lg * 4 + r;
      ao4[(size_t)sp * 2097152 + (size_t)(b * 2048 + qrow) * 512 + h * 64 + nt * 16 + lr] =
          f2bf(oacc[nt][r]);
    }
}

// ----------------------------------------------------------------
extern "C" void kernel_launch(void* const* d_in, const int* in_sizes, int n_in,
                              void* d_out, int out_size, void* d_ws, size_t ws_size,
                              hipStream_t stream) {
  const float* X[3] = {(const float*)d_in[0], (const float*)d_in[1], (const float*)d_in[2]};
  const float* G1[3] = {(const float*)d_in[3], (const float*)d_in[9], (const float*)d_in[15]};
  const float* B1[3] = {(const float*)d_in[4], (const float*)d_in[10], (const float*)d_in[16]};
  const float* WQKV[3] = {(const float*)d_in[5], (const float*)d_in[11], (const float*)d_in[17]};
  const float* RMS[3] = {(const float*)d_in[6], (const float*)d_in[12], (const float*)d_in[18]};
  const float* WO[3] = {(const float*)d_in[7], (const float*)d_in[13], (const float*)d_in[19]};
  const float* BO[3] = {(const float*)d_in[8], (const float*)d_in[14], (const float*)d_in[20]};
  const float* G2 = (const float*)d_in[21];
  const float* B2 = (const float*)d_in[22];
  const float* WFC1 = (const float*)d_in[23];
  const float* BFC1 = (const float*)d_in[24];
  const float* WFC2 = (const float*)d_in[25];
  const float* BFC2 = (const float*)d_in[26];
  float* dout = (float*)d_out;

  // Workspace layout (u16 element offsets). Peak ~39 MiB (proven-safe range).
  u16* W = (u16*)d_ws;
  u16* wqkvT = W;                  // [3][1536][256]  0 .. 1,179,648
  u16* woT = W + 1179648;          // [3][256][512]   .. 1,572,864
  u16* fc1T = W + 1572864;         // [1024][768]     .. 2,359,296
  u16* fc2T = W + 2359296;         // [768][1024]     .. 3,145,728
  u16* xn = W + 3145728;           // [3][4096][256]  .. 6,291,456
  u16* qz = W + 6291456;           // [16][2048][64]  .. 8,388,608   (per-branch reuse)
  u16* kz = W + 8388608;           //                 .. 10,485,760
  u16* vz = W + 10485760;          //                 .. 12,582,912
  u16* ao4 = W + 12582912;         // [2][4096][512]  .. 16,777,216
  u16* aoN = W + 16777216;         // [4096][512]     .. 18,874,368
  // Stage B overlays (stage-A buffers dead by then):
  u16* ln2b = W + 6291456;         // [4096][768]     .. 9,437,184
  u16* hbuf = W + 9437184;         // [4096][1024]    .. 13,631,488

  // 1) all weight transposes, one launch
  TrArgs ta;
  const float* srcs[8] = {WQKV[0], WQKV[1], WQKV[2], WO[0], WO[1], WO[2], WFC1, WFC2};
  u16* dsts[8] = {wqkvT, wqkvT + 393216, wqkvT + 786432, woT, woT + 131072, woT + 262144, fc1T, fc2T};
  int Ks_[8] = {256, 256, 256, 512, 512, 512, 768, 1024};
  int Ns_[8] = {1536, 1536, 1536, 256, 256, 256, 1024, 768};
  int tst[9] = {0, 384, 768, 1152, 1280, 1408, 1536, 2304, 3072};
  for (int i = 0; i < 8; i++) {
    ta.src[i] = srcs[i];
    ta.dst[i] = dsts[i];
    ta.K[i] = Ks_[i];
    ta.N[i] = Ns_[i];
    ta.tstart[i] = tst[i];
  }
  ta.tstart[8] = tst[8];
  hipLaunchKernelGGL(tr_kernel, dim3(3072), dim3(256), 0, stream, ta);

  // 2) LN1 batched
  LN1Args la;
  for (int i = 0; i < 3; i++) {
    la.x[i] = X[i];
    la.g[i] = G1[i];
    la.b[i] = B1[i];
  }
  la.out = xn;
  hipLaunchKernelGGL(ln1_kernel, dim3(1024, 3), dim3(256), 0, stream, la);

  // 3) per-branch pipeline
  for (int z = 0; z < 3; z++) {
    GemmQkvArgs gq = {xn + (size_t)z * 1048576, wqkvT + (size_t)z * 393216, qz, kz, vz};
    hipLaunchKernelGGL(gemmqkv_kernel, dim3(12, 32), dim3(256), 0, stream, gq);

    hipLaunchKernelGGL(attn_kernel, dim3(32, 16, 2), dim3(256), 0, stream, qz, kz, vz, ao4);

    hipLaunchKernelGGL(rms_sum_kernel, dim3(1024), dim3(256), 0, stream, ao4, RMS[z], aoN);

    Gemm64Args gw = {aoN, woT + (size_t)z * 131072, BO[z], X[z], dout + (size_t)z * 1048576};
    hipLaunchKernelGGL(gemm64_kernel, dim3(4, 64), dim3(256), 0, stream, gw);
  }

  // 4) LN2 -> bf16
  hipLaunchKernelGGL(ln2_kernel, dim3(1024), dim3(256), 0, stream, dout, G2, B2, ln2b);

  // 5) FC1 (M=4096,N=1024,K=768) + gelu -> hbuf
  GemmMlpArgs g1 = {};
  g1.A = ln2b;
  g1.Bt = fc1T;
  g1.K = 768;
  g1.bias = BFC1;
  g1.oh = hbuf;
  hipLaunchKernelGGL(gemmmlp_kernel<0>, dim3(16, 32), dim3(256), 0, stream, g1);

  // 6) FC2 (M=4096,N=768,K=1024) + bias + residual RMW on d_out
  GemmMlpArgs g2 = {};
  g2.A = hbuf;
  g2.Bt = fc2T;
  g2.K = 1024;
  g2.bias = BFC2;
  g2.outf = dout;
  hipLaunchKernelGGL(gemmmlp_kernel<1>, dim3(12, 32), dim3(256), 0, stream, g2);
}

// Round 8
// 234.081 us; speedup vs baseline: 1.8738x; 1.1148x over previous
//
#include <hip/hip_runtime.h>

using u16 = unsigned short;
typedef __attribute__((ext_vector_type(4))) float f32x4;
typedef __attribute__((ext_vector_type(8))) short s16x8;
typedef __attribute__((ext_vector_type(4))) unsigned short u16x4;

#define MFMA(a, b, c) __builtin_amdgcn_mfma_f32_16x16x32_bf16((a), (b), (c), 0, 0, 0)

__device__ __forceinline__ u16 f2bf(float f) {
  unsigned u = __float_as_uint(f);
  u += 0x7fff + ((u >> 16) & 1);
  return (u16)(u >> 16);
}
__device__ __forceinline__ float bf2f(u16 h) {
  return __uint_as_float((unsigned)h << 16);
}

// ---------------------------------------------------------------- transpose+convert all weights, one launch
struct TrArgs {
  const float* src[8];
  u16* dst[8];
  int K[8], N[8];
  int tstart[9];
};
__global__ __launch_bounds__(256) void tr_kernel(TrArgs a) {
  __shared__ float t[32][33];
  int tile = blockIdx.x;
  int m = 0;
  while (tile >= a.tstart[m + 1]) m++;
  int ti = tile - a.tstart[m];
  int K = a.K[m], N = a.N[m];
  int ntn = N >> 5;
  int tk = ti / ntn;
  int k0 = tk << 5, n0 = (ti - tk * ntn) << 5;
  int r = threadIdx.x >> 3, c4 = (threadIdx.x & 7) << 2;
  const float* s = a.src[m] + (size_t)(k0 + r) * N + n0 + c4;
  float4 v = *(const float4*)s;
  t[r][c4 + 0] = v.x;
  t[r][c4 + 1] = v.y;
  t[r][c4 + 2] = v.z;
  t[r][c4 + 3] = v.w;
  __syncthreads();
  size_t o = (size_t)(n0 + r) * K + k0 + c4;
  u16* d = a.dst[m];
#pragma unroll
  for (int j = 0; j < 4; j++) d[o + j] = f2bf(t[c4 + j][r]);
}

// ---------------------------------------------------------------- LayerNorm (W=256), batched over branches
struct LN1Args {
  const float* x[3];
  const float* g[3];
  const float* b[3];
  u16* out;  // [3][4096][256]
};
__global__ __launch_bounds__(256) void ln1_kernel(LN1Args a) {
  int lane = threadIdx.x & 63, wid = threadIdx.x >> 6;
  int row = blockIdx.x * 4 + wid;
  int br = blockIdx.y;
  const float* xp = a.x[br] + (size_t)row * 256;
  float v[4], s = 0.f, s2 = 0.f;
#pragma unroll
  for (int j = 0; j < 4; j++) {
    v[j] = xp[lane + 64 * j];
    s += v[j];
    s2 += v[j] * v[j];
  }
#pragma unroll
  for (int m = 32; m; m >>= 1) {
    s += __shfl_xor(s, m);
    s2 += __shfl_xor(s2, m);
  }
  float mean = s * (1.f / 256.f);
  float rstd = rsqrtf(s2 * (1.f / 256.f) - mean * mean + 1e-5f);
  u16* o = a.out + (size_t)br * 1048576 + (size_t)row * 256;
#pragma unroll
  for (int j = 0; j < 4; j++) {
    int c = lane + 64 * j;
    o[c] = f2bf((v[j] - mean) * rstd * a.g[br][c] + a.b[br][c]);
  }
}

// ---------------------------------------------------------------- LayerNorm2 (W=768) -> bf16
__global__ __launch_bounds__(256) void ln2_kernel(const float* xc, const float* g, const float* b,
                                                  u16* oh) {
  int lane = threadIdx.x & 63, wid = threadIdx.x >> 6;
  int row = blockIdx.x * 4 + wid;
  float v[12], s = 0.f, s2 = 0.f;
#pragma unroll
  for (int j = 0; j < 12; j++) {
    int c = lane + 64 * j;
    v[j] = xc[(size_t)(c >> 8) * 1048576 + (size_t)row * 256 + (c & 255)];
    s += v[j];
    s2 += v[j] * v[j];
  }
#pragma unroll
  for (int m = 32; m; m >>= 1) {
    s += __shfl_xor(s, m);
    s2 += __shfl_xor(s2, m);
  }
  float mean = s * (1.f / 768.f);
  float rstd = rsqrtf(s2 * (1.f / 768.f) - mean * mean + 1e-5f);
#pragma unroll
  for (int j = 0; j < 12; j++) {
    int c = lane + 64 * j;
    oh[(size_t)row * 768 + c] = f2bf((v[j] - mean) * rstd * g[c] + b[c]);
  }
}

// ---------------------------------------------------------------- sum 4 KV-split partials + RMSNorm -> aoN
__global__ __launch_bounds__(256) void rms_sum_kernel(const u16* ao4, const float* sc, u16* aoN) {
  int lane = threadIdx.x & 63, wid = threadIdx.x >> 6;
  int row = blockIdx.x * 4 + wid;
  const u16* p0 = ao4 + (size_t)row * 512;
  const u16* p1 = p0 + 2097152;
  const u16* p2 = p0 + 4194304;
  const u16* p3 = p0 + 6291456;
  float v[8], s2 = 0.f;
#pragma unroll
  for (int j = 0; j < 8; j++) {
    int c = lane + 64 * j;
    v[j] = (bf2f(p0[c]) + bf2f(p1[c])) + (bf2f(p2[c]) + bf2f(p3[c]));
    s2 += v[j] * v[j];
  }
#pragma unroll
  for (int m = 32; m; m >>= 1) s2 += __shfl_xor(s2, m);
  float inv = 1.f / (sqrtf(s2) * 0.044194173824159216f + 1e-8f);  // *512^-0.5
#pragma unroll
  for (int j = 0; j < 8; j++) {
    int c = lane + 64 * j;
    aoN[(size_t)row * 512 + c] = f2bf(v[j] * inv * sc[c]);
  }
}

// ---------------------------------------------------------------- QKV GEMM 128x128 (M=4096,N=1536,K=256)
// q,k written natural [bh][n][64] (q scaled 0.125); v written TRANSPOSED [bh][d=64][n=2048].
struct GemmQkvArgs {
  const u16* A;
  const u16* Bt;
  u16 *q, *k, *v;
};
__global__ __launch_bounds__(256) void gemmqkv_kernel(GemmQkvArgs g) {
  __shared__ u16 As[128][40];
  __shared__ u16 Bs[128][40];
  const int tid = threadIdx.x;
  const int lane = tid & 63, wid = tid >> 6;
  const int wm = wid >> 1, wn = wid & 1;
  const int lr = lane & 15, lg = lane >> 4;
  const int m0 = blockIdx.y * 128, n0 = blockIdx.x * 128;
  const int K = 256;
  f32x4 acc[4][4] = {};
  const int sr = tid >> 1, sh = (tid & 1) << 4;
  const u16* ga = g.A + (size_t)(m0 + sr) * K + sh;
  const u16* gb = g.Bt + (size_t)(n0 + sr) * K + sh;
  for (int k0 = 0; k0 < K; k0 += 32) {
    s16x8 a0 = *(const s16x8*)(ga + k0);
    s16x8 a1 = *(const s16x8*)(ga + k0 + 8);
    s16x8 b0 = *(const s16x8*)(gb + k0);
    s16x8 b1 = *(const s16x8*)(gb + k0 + 8);
    __syncthreads();
    *(s16x8*)&As[sr][sh] = a0;
    *(s16x8*)&As[sr][sh + 8] = a1;
    *(s16x8*)&Bs[sr][sh] = b0;
    *(s16x8*)&Bs[sr][sh + 8] = b1;
    __syncthreads();
    s16x8 af[4], bfr[4];
#pragma unroll
    for (int mt = 0; mt < 4; mt++) af[mt] = *(const s16x8*)&As[wm * 64 + mt * 16 + lr][lg * 8];
#pragma unroll
    for (int nt = 0; nt < 4; nt++) bfr[nt] = *(const s16x8*)&Bs[wn * 64 + nt * 16 + lr][lg * 8];
#pragma unroll
    for (int mt = 0; mt < 4; mt++)
#pragma unroll
      for (int nt = 0; nt < 4; nt++) acc[mt][nt] = MFMA(af[mt], bfr[nt], acc[mt][nt]);
  }
  const int seg = n0 >> 9;  // uniform per block (n0 multiple of 128)
  if (seg == 2) {
    // V transposed: each thread's 4 r-values are n-consecutive at fixed d -> 8B stores
#pragma unroll
    for (int mt = 0; mt < 4; mt++) {
      int nbase = m0 + wm * 64 + mt * 16 + lg * 4;
      int b = nbase >> 11, n = nbase & 2047;
#pragma unroll
      for (int nt = 0; nt < 4; nt++) {
        int col = n0 + wn * 64 + nt * 16 + lr;
        int hh = (col >> 6) & 7, d = col & 63;
        u16x4 w;
#pragma unroll
        for (int r = 0; r < 4; r++) w[r] = f2bf(acc[mt][nt][r]);
        *(u16x4*)(g.v + (size_t)((b << 3) + hh) * 131072 + (size_t)d * 2048 + n) = w;
      }
    }
  } else {
#pragma unroll
    for (int mt = 0; mt < 4; mt++)
#pragma unroll
      for (int nt = 0; nt < 4; nt++)
#pragma unroll
        for (int r = 0; r < 4; r++) {
          int row = m0 + wm * 64 + mt * 16 + lg * 4 + r;
          int col = n0 + wn * 64 + nt * 16 + lr;
          float val = acc[mt][nt][r];
          int hh = (col >> 6) & 7, d = col & 63;
          u16* dst = seg == 0 ? g.q : g.k;
          float scv = (seg == 0) ? 0.125f : 1.0f;
          int b = row >> 11, n = row & 2047;
          dst[(size_t)((b << 3) + hh) * 131072 + (size_t)n * 64 + d] = f2bf(val * scv);
        }
  }
}

// ---------------------------------------------------------------- WO GEMM 64x64 tile (+bias+residual->fp32)
struct Gemm64Args {
  const u16* A;   // [4096][512]
  const u16* Bt;  // [256][512]
  const float* bias;
  const float* res;
  float* outf;
};
__global__ __launch_bounds__(256) void gemm64_kernel(Gemm64Args g) {
  __shared__ u16 As[64][40];
  __shared__ u16 Bs[64][40];
  const int tid = threadIdx.x;
  const int lane = tid & 63, wid = tid >> 6;
  const int wm = wid >> 1, wn = wid & 1;
  const int lr = lane & 15, lg = lane >> 4;
  const int m0 = blockIdx.y * 64, n0 = blockIdx.x * 64;
  const int K = 512;
  f32x4 acc[2][2] = {};
  const int sr = tid >> 2, sh8 = (tid & 3) << 3;
  const u16* ga = g.A + (size_t)(m0 + sr) * K + sh8;
  const u16* gb = g.Bt + (size_t)(n0 + sr) * K + sh8;
  for (int k0 = 0; k0 < K; k0 += 32) {
    s16x8 a0 = *(const s16x8*)(ga + k0);
    s16x8 b0 = *(const s16x8*)(gb + k0);
    __syncthreads();
    *(s16x8*)&As[sr][sh8] = a0;
    *(s16x8*)&Bs[sr][sh8] = b0;
    __syncthreads();
    s16x8 af[2], bfr[2];
#pragma unroll
    for (int mt = 0; mt < 2; mt++) af[mt] = *(const s16x8*)&As[wm * 32 + mt * 16 + lr][lg * 8];
#pragma unroll
    for (int nt = 0; nt < 2; nt++) bfr[nt] = *(const s16x8*)&Bs[wn * 32 + nt * 16 + lr][lg * 8];
#pragma unroll
    for (int mt = 0; mt < 2; mt++)
#pragma unroll
      for (int nt = 0; nt < 2; nt++) acc[mt][nt] = MFMA(af[mt], bfr[nt], acc[mt][nt]);
  }
#pragma unroll
  for (int mt = 0; mt < 2; mt++)
#pragma unroll
    for (int nt = 0; nt < 2; nt++)
#pragma unroll
      for (int r = 0; r < 4; r++) {
        int row = m0 + wm * 32 + mt * 16 + lg * 4 + r;
        int col = n0 + wn * 32 + nt * 16 + lr;
        float val = acc[mt][nt][r] + g.bias[col] + g.res[(size_t)row * 256 + col];
        g.outf[(size_t)row * 256 + col] = val;
      }
}

// ---------------------------------------------------------------- MLP GEMM, 128x64 tile, single bf16 term
struct GemmMlpArgs {
  const u16 *A, *Bt;
  int K;
  const float* bias;
  u16* oh;      // EPI 0
  float* outf;  // EPI 1
};
template <int EPI>
__global__ __launch_bounds__(256) void gemmmlp_kernel(GemmMlpArgs g) {
  __shared__ u16 As[128][40], Bs[64][40];
  const int tid = threadIdx.x;
  const int lane = tid & 63, wid = tid >> 6;
  const int wm = wid >> 1, wn = wid & 1;
  const int lr = lane & 15, lg = lane >> 4;
  const int m0 = blockIdx.y * 128, n0 = blockIdx.x * 64;
  const int K = g.K;
  f32x4 acc[4][2] = {};
  const int sra = tid >> 1, sha = (tid & 1) << 4;
  const int srb = tid >> 2, shb = (tid & 3) << 3;
  const u16* ga = g.A + (size_t)(m0 + sra) * K + sha;
  const u16* gb = g.Bt + (size_t)(n0 + srb) * K + shb;
  for (int k0 = 0; k0 < K; k0 += 32) {
    s16x8 a0 = *(const s16x8*)(ga + k0);
    s16x8 a1 = *(const s16x8*)(ga + k0 + 8);
    s16x8 b0 = *(const s16x8*)(gb + k0);
    __syncthreads();
    *(s16x8*)&As[sra][sha] = a0;
    *(s16x8*)&As[sra][sha + 8] = a1;
    *(s16x8*)&Bs[srb][shb] = b0;
    __syncthreads();
    s16x8 af[4], bfr[2];
#pragma unroll
    for (int mt = 0; mt < 4; mt++) af[mt] = *(const s16x8*)&As[wm * 64 + mt * 16 + lr][lg * 8];
#pragma unroll
    for (int nt = 0; nt < 2; nt++) bfr[nt] = *(const s16x8*)&Bs[wn * 32 + nt * 16 + lr][lg * 8];
#pragma unroll
    for (int mt = 0; mt < 4; mt++)
#pragma unroll
      for (int nt = 0; nt < 2; nt++) acc[mt][nt] = MFMA(af[mt], bfr[nt], acc[mt][nt]);
  }
#pragma unroll
  for (int mt = 0; mt < 4; mt++)
#pragma unroll
    for (int nt = 0; nt < 2; nt++)
#pragma unroll
      for (int r = 0; r < 4; r++) {
        int row = m0 + wm * 64 + mt * 16 + lg * 4 + r;
        int col = n0 + wn * 32 + nt * 16 + lr;
        float val = acc[mt][nt][r] + g.bias[col];
        if (EPI == 0) {
          float ge = 0.5f * val * (1.0f + erff(val * 0.70710678118654752f));
          g.oh[(size_t)row * 1024 + col] = f2bf(ge);
        } else {
          int chunk = col >> 8, cc = col & 255;
          float* p = g.outf + (size_t)chunk * 1048576 + (size_t)row * 256 + cc;
          *p = val + *p;
        }
      }
}

// ---------------------------------------------------------------- ReLU attention v4 (R4-proven math)
// QBLK=128 (4 waves x 32 q), KV-split=4 (8 kv-tiles of 64). V pre-transposed in global:
// Vt LDS staged with vector writes (no scalar transpose, no swizzle). Reg prefetch of next tile.
__global__ __launch_bounds__(256) void attn_kernel(const u16* q, const u16* k, const u16* vT, u16* ao4) {
  __shared__ u16 Ks[64][72];   // [kv][d]
  __shared__ u16 Vt[64][72];   // [d][kv]
  __shared__ u16 Ps[128][72];  // [q][kv]
  const int tid = threadIdx.x;
  const int lane = tid & 63, wid = tid >> 6;
  const int lr = lane & 15, lg = lane >> 4;
  const int qb = blockIdx.x, bh = blockIdx.y, sp = blockIdx.z;
  const size_t boff = (size_t)bh * 131072;
  const u16* qp = q + boff;
  const u16* kp = k + boff;
  const u16* vp = vT + boff;
  s16x8 qf[2][2];
#pragma unroll
  for (int mt = 0; mt < 2; mt++)
#pragma unroll
    for (int ks = 0; ks < 2; ks++)
      qf[mt][ks] = *(const s16x8*)(qp + (size_t)(qb * 128 + wid * 32 + mt * 16 + lr) * 64 + ks * 32 + lg * 8);
  f32x4 oacc[2][4] = {};
  const int sr = tid >> 2, sc = (tid & 3) << 4;
  const u16* kg = kp + sr * 64 + sc;    // K rows [kv][d]
  const u16* vg = vp + sr * 2048 + sc;  // vT rows [d][n]; col offset kt*64+sc
  const int ktL = sp * 8, ktH = ktL + 8;
  s16x8 kv0 = *(const s16x8*)(kg + ktL * 4096);
  s16x8 kv1 = *(const s16x8*)(kg + ktL * 4096 + 8);
  s16x8 vv0 = *(const s16x8*)(vg + ktL * 64);
  s16x8 vv1 = *(const s16x8*)(vg + ktL * 64 + 8);
  for (int kt = ktL; kt < ktH; kt++) {
    __syncthreads();  // prev tile's LDS reads done
    *(s16x8*)&Ks[sr][sc] = kv0;
    *(s16x8*)&Ks[sr][sc + 8] = kv1;
    *(s16x8*)&Vt[sr][sc] = vv0;
    *(s16x8*)&Vt[sr][sc + 8] = vv1;
    __syncthreads();
    const int nx = (kt + 1 < ktH) ? kt + 1 : kt;
    kv0 = *(const s16x8*)(kg + nx * 4096);
    kv1 = *(const s16x8*)(kg + nx * 4096 + 8);
    vv0 = *(const s16x8*)(vg + nx * 64);
    vv1 = *(const s16x8*)(vg + nx * 64 + 8);
    // S = Q K^T
    f32x4 sacc[2][4] = {};
#pragma unroll
    for (int nt = 0; nt < 4; nt++)
#pragma unroll
      for (int ks = 0; ks < 2; ks++) {
        s16x8 kf = *(const s16x8*)&Ks[nt * 16 + lr][ks * 32 + lg * 8];
        sacc[0][nt] = MFMA(qf[0][ks], kf, sacc[0][nt]);
        sacc[1][nt] = MFMA(qf[1][ks], kf, sacc[1][nt]);
      }
    // P = relu(S) -> LDS
#pragma unroll
    for (int mt = 0; mt < 2; mt++)
#pragma unroll
      for (int nt = 0; nt < 4; nt++)
#pragma unroll
        for (int r = 0; r < 4; r++) {
          float s = sacc[mt][nt][r];
          Ps[wid * 32 + mt * 16 + lg * 4 + r][nt * 16 + lr] = f2bf(s > 0.f ? s : 0.f);
        }
    __syncthreads();
    // O += P V
#pragma unroll
    for (int ks = 0; ks < 2; ks++) {
      s16x8 pa0 = *(const s16x8*)&Ps[wid * 32 + lr][ks * 32 + lg * 8];
      s16x8 pa1 = *(const s16x8*)&Ps[wid * 32 + 16 + lr][ks * 32 + lg * 8];
#pragma unroll
      for (int nt = 0; nt < 4; nt++) {
        s16x8 vf = *(const s16x8*)&Vt[nt * 16 + lr][ks * 32 + lg * 8];
        oacc[0][nt] = MFMA(pa0, vf, oacc[0][nt]);
        oacc[1][nt] = MFMA(pa1, vf, oacc[1][nt]);
      }
    }
  }
  const int b = bh >> 3, h = bh & 7;
#pragma unroll
  for (int mt = 0; mt < 2; mt++)
#pragma unroll
    for (int nt = 0; nt < 4; nt++)
#pragma unroll
      for (int r = 0; r < 4; r++) {
        int qrow = qb * 128 + wid * 32 + mt * 16 + lg * 4 + r;
        ao4[(size_t)sp * 2097152 + (size_t)(b * 2048 + qrow) * 512 + h * 64 + nt * 16 + lr] =
            f2bf(oacc[mt][nt][r]);
      }
}

// ----------------------------------------------------------------
extern "C" void kernel_launch(void* const* d_in, const int* in_sizes, int n_in,
                              void* d_out, int out_size, void* d_ws, size_t ws_size,
                              hipStream_t stream) {
  const float* X[3] = {(const float*)d_in[0], (const float*)d_in[1], (const float*)d_in[2]};
  const float* G1[3] = {(const float*)d_in[3], (const float*)d_in[9], (const float*)d_in[15]};
  const float* B1[3] = {(const float*)d_in[4], (const float*)d_in[10], (const float*)d_in[16]};
  const float* WQKV[3] = {(const float*)d_in[5], (const float*)d_in[11], (const float*)d_in[17]};
  const float* RMS[3] = {(const float*)d_in[6], (const float*)d_in[12], (const float*)d_in[18]};
  const float* WO[3] = {(const float*)d_in[7], (const float*)d_in[13], (const float*)d_in[19]};
  const float* BO[3] = {(const float*)d_in[8], (const float*)d_in[14], (const float*)d_in[20]};
  const float* G2 = (const float*)d_in[21];
  const float* B2 = (const float*)d_in[22];
  const float* WFC1 = (const float*)d_in[23];
  const float* BFC1 = (const float*)d_in[24];
  const float* WFC2 = (const float*)d_in[25];
  const float* BFC2 = (const float*)d_in[26];
  float* dout = (float*)d_out;

  // Workspace layout (u16 element offsets). Peak 23,068,672 elem = 44 MiB.
  u16* W = (u16*)d_ws;
  u16* wqkvT = W;                  // [3][1536][256]  0 .. 1,179,648
  u16* woT = W + 1179648;          // [3][256][512]   .. 1,572,864
  u16* fc1T = W + 1572864;         // [1024][768]     .. 2,359,296
  u16* fc2T = W + 2359296;         // [768][1024]     .. 3,145,728
  u16* xn = W + 3145728;           // [3][4096][256]  .. 6,291,456
  u16* qz = W + 6291456;           // [16][2048][64]  .. 8,388,608   (per-branch reuse)
  u16* kz = W + 8388608;           //                 .. 10,485,760
  u16* vz = W + 10485760;          // [16][64][2048] (transposed) .. 12,582,912
  u16* ao4 = W + 12582912;         // [4][4096][512]  .. 20,971,520
  u16* aoN = W + 20971520;         // [4096][512]     .. 23,068,672
  // Stage B overlays (stage-A buffers dead by then):
  u16* ln2b = W + 6291456;         // [4096][768]     .. 9,437,184
  u16* hbuf = W + 9437184;         // [4096][1024]    .. 13,631,488

  // 1) all weight transposes, one launch
  TrArgs ta;
  const float* srcs[8] = {WQKV[0], WQKV[1], WQKV[2], WO[0], WO[1], WO[2], WFC1, WFC2};
  u16* dsts[8] = {wqkvT, wqkvT + 393216, wqkvT + 786432, woT, woT + 131072, woT + 262144, fc1T, fc2T};
  int Ks_[8] = {256, 256, 256, 512, 512, 512, 768, 1024};
  int Ns_[8] = {1536, 1536, 1536, 256, 256, 256, 1024, 768};
  int tst[9] = {0, 384, 768, 1152, 1280, 1408, 1536, 2304, 3072};
  for (int i = 0; i < 8; i++) {
    ta.src[i] = srcs[i];
    ta.dst[i] = dsts[i];
    ta.K[i] = Ks_[i];
    ta.N[i] = Ns_[i];
    ta.tstart[i] = tst[i];
  }
  ta.tstart[8] = tst[8];
  hipLaunchKernelGGL(tr_kernel, dim3(3072), dim3(256), 0, stream, ta);

  // 2) LN1 batched
  LN1Args la;
  for (int i = 0; i < 3; i++) {
    la.x[i] = X[i];
    la.g[i] = G1[i];
    la.b[i] = B1[i];
  }
  la.out = xn;
  hipLaunchKernelGGL(ln1_kernel, dim3(1024, 3), dim3(256), 0, stream, la);

  // 3) per-branch pipeline
  for (int z = 0; z < 3; z++) {
    GemmQkvArgs gq = {xn + (size_t)z * 1048576, wqkvT + (size_t)z * 393216, qz, kz, vz};
    hipLaunchKernelGGL(gemmqkv_kernel, dim3(12, 32), dim3(256), 0, stream, gq);

    hipLaunchKernelGGL(attn_kernel, dim3(16, 16, 4), dim3(256), 0, stream, qz, kz, vz, ao4);

    hipLaunchKernelGGL(rms_sum_kernel, dim3(1024), dim3(256), 0, stream, ao4, RMS[z], aoN);

    Gemm64Args gw = {aoN, woT + (size_t)z * 131072, BO[z], X[z], dout + (size_t)z * 1048576};
    hipLaunchKernelGGL(gemm64_kernel, dim3(4, 64), dim3(256), 0, stream, gw);
  }

  // 4) LN2 -> bf16
  hipLaunchKernelGGL(ln2_kernel, dim3(1024), dim3(256), 0, stream, dout, G2, B2, ln2b);

  // 5) FC1 (M=4096,N=1024,K=768) + gelu -> hbuf
  GemmMlpArgs g1 = {};
  g1.A = ln2b;
  g1.Bt = fc1T;
  g1.K = 768;
  g1.bias = BFC1;
  g1.oh = hbuf;
  hipLaunchKernelGGL(gemmmlp_kernel<0>, dim3(16, 32), dim3(256), 0, stream, g1);

  // 6) FC2 (M=4096,N=768,K=1024) + bias + residual RMW on d_out
  GemmMlpArgs g2 = {};
  g2.A = hbuf;
  g2.Bt = fc2T;
  g2.K = 1024;
  g2.bias = BFC2;
  g2.outf = dout;
  hipLaunchKernelGGL(gemmmlp_kernel<1>, dim3(12, 32), dim3(256), 0, stream, g2);
}

// Round 9
// 188.074 us; speedup vs baseline: 2.3322x; 1.2446x over previous
//
#include <hip/hip_runtime.h>

using u16 = unsigned short;
typedef __attribute__((ext_vector_type(4))) float f32x4;
typedef __attribute__((ext_vector_type(8))) short s16x8;
typedef __attribute__((ext_vector_type(4))) unsigned short u16x4;

#define MFMA(a, b, c) __builtin_amdgcn_mfma_f32_16x16x32_bf16((a), (b), (c), 0, 0, 0)

__device__ __forceinline__ u16 f2bf(float f) {
  unsigned u = __float_as_uint(f);
  u += 0x7fff + ((u >> 16) & 1);
  return (u16)(u >> 16);
}
__device__ __forceinline__ float bf2f(u16 h) {
  return __uint_as_float((unsigned)h << 16);
}

// ---------------------------------------------------------------- transpose+convert all weights, one launch
struct TrArgs {
  const float* src[8];
  u16* dst[8];
  int K[8], N[8];
  int tstart[9];
};
__global__ __launch_bounds__(256) void tr_kernel(TrArgs a) {
  __shared__ float t[32][33];
  int tile = blockIdx.x;
  int m = 0;
  while (tile >= a.tstart[m + 1]) m++;
  int ti = tile - a.tstart[m];
  int K = a.K[m], N = a.N[m];
  int ntn = N >> 5;
  int tk = ti / ntn;
  int k0 = tk << 5, n0 = (ti - tk * ntn) << 5;
  int r = threadIdx.x >> 3, c4 = (threadIdx.x & 7) << 2;
  const float* s = a.src[m] + (size_t)(k0 + r) * N + n0 + c4;
  float4 v = *(const float4*)s;
  t[r][c4 + 0] = v.x;
  t[r][c4 + 1] = v.y;
  t[r][c4 + 2] = v.z;
  t[r][c4 + 3] = v.w;
  __syncthreads();
  size_t o = (size_t)(n0 + r) * K + k0 + c4;
  u16* d = a.dst[m];
#pragma unroll
  for (int j = 0; j < 4; j++) d[o + j] = f2bf(t[c4 + j][r]);
}

// ---------------------------------------------------------------- LayerNorm (W=256), batched over branches
struct LN1Args {
  const float* x[3];
  const float* g[3];
  const float* b[3];
  u16* out;  // [3][4096][256]
};
__global__ __launch_bounds__(256) void ln1_kernel(LN1Args a) {
  int lane = threadIdx.x & 63, wid = threadIdx.x >> 6;
  int row = blockIdx.x * 4 + wid;
  int br = blockIdx.y;
  const float* xp = a.x[br] + (size_t)row * 256;
  float v[4], s = 0.f, s2 = 0.f;
#pragma unroll
  for (int j = 0; j < 4; j++) {
    v[j] = xp[lane + 64 * j];
    s += v[j];
    s2 += v[j] * v[j];
  }
#pragma unroll
  for (int m = 32; m; m >>= 1) {
    s += __shfl_xor(s, m);
    s2 += __shfl_xor(s2, m);
  }
  float mean = s * (1.f / 256.f);
  float rstd = rsqrtf(s2 * (1.f / 256.f) - mean * mean + 1e-5f);
  u16* o = a.out + (size_t)br * 1048576 + (size_t)row * 256;
#pragma unroll
  for (int j = 0; j < 4; j++) {
    int c = lane + 64 * j;
    o[c] = f2bf((v[j] - mean) * rstd * a.g[br][c] + a.b[br][c]);
  }
}

// ---------------------------------------------------------------- LayerNorm2 (W=768) -> bf16
__global__ __launch_bounds__(256) void ln2_kernel(const float* xc, const float* g, const float* b,
                                                  u16* oh) {
  int lane = threadIdx.x & 63, wid = threadIdx.x >> 6;
  int row = blockIdx.x * 4 + wid;
  float v[12], s = 0.f, s2 = 0.f;
#pragma unroll
  for (int j = 0; j < 12; j++) {
    int c = lane + 64 * j;
    v[j] = xc[(size_t)(c >> 8) * 1048576 + (size_t)row * 256 + (c & 255)];
    s += v[j];
    s2 += v[j] * v[j];
  }
#pragma unroll
  for (int m = 32; m; m >>= 1) {
    s += __shfl_xor(s, m);
    s2 += __shfl_xor(s2, m);
  }
  float mean = s * (1.f / 768.f);
  float rstd = rsqrtf(s2 * (1.f / 768.f) - mean * mean + 1e-5f);
#pragma unroll
  for (int j = 0; j < 12; j++) {
    int c = lane + 64 * j;
    oh[(size_t)row * 768 + c] = f2bf((v[j] - mean) * rstd * g[c] + b[c]);
  }
}

// ---------------------------------------------------------------- sum NSPLIT KV partials + RMSNorm -> aoN
struct RmsArgs {
  const u16* ao4;
  const float* sc[3];
  u16* aoN;
  int brAo, brAoN;  // per-branch element strides (0 in serial mode)
};
template <int NSPLIT>
__global__ __launch_bounds__(256) void rms_sum_kernel(RmsArgs a) {
  int lane = threadIdx.x & 63, wid = threadIdx.x >> 6;
  int row = blockIdx.x * 4 + wid;
  int br = blockIdx.y;
  const u16* base = a.ao4 + (size_t)br * a.brAo + (size_t)row * 512;
  float v[8], s2 = 0.f;
#pragma unroll
  for (int j = 0; j < 8; j++) {
    int c = lane + 64 * j;
    float acc = 0.f;
#pragma unroll
    for (int s = 0; s < NSPLIT; s++) acc += bf2f(base[(size_t)s * 2097152 + c]);
    v[j] = acc;
    s2 += v[j] * v[j];
  }
#pragma unroll
  for (int m = 32; m; m >>= 1) s2 += __shfl_xor(s2, m);
  float inv = 1.f / (sqrtf(s2) * 0.044194173824159216f + 1e-8f);  // *512^-0.5
  const float* sc = a.sc[br];
  u16* o = a.aoN + (size_t)br * a.brAoN + (size_t)row * 512;
#pragma unroll
  for (int j = 0; j < 8; j++) {
    int c = lane + 64 * j;
    o[c] = f2bf(v[j] * inv * sc[c]);
  }
}

// ---------------------------------------------------------------- QKV GEMM 128x128 (M=4096,N=1536,K=256)
// q,k written natural [bh][n][64] (q scaled 0.125); v written TRANSPOSED [bh][d=64][n=2048].
// blockIdx.z = branch (strides fixed: A 1048576, Bt 393216, qkv 2097152); serial mode: grid z=1, offset ptrs.
struct GemmQkvArgs {
  const u16* A;
  const u16* Bt;
  u16 *q, *k, *v;
};
__global__ __launch_bounds__(256) void gemmqkv_kernel(GemmQkvArgs g) {
  __shared__ u16 As[128][40];
  __shared__ u16 Bs[128][40];
  const int tid = threadIdx.x;
  const int lane = tid & 63, wid = tid >> 6;
  const int wm = wid >> 1, wn = wid & 1;
  const int lr = lane & 15, lg = lane >> 4;
  const int m0 = blockIdx.y * 128, n0 = blockIdx.x * 128;
  const int z = blockIdx.z;
  const int K = 256;
  f32x4 acc[4][4] = {};
  const int sr = tid >> 1, sh = (tid & 1) << 4;
  const u16* ga = g.A + (size_t)z * 1048576 + (size_t)(m0 + sr) * K + sh;
  const u16* gb = g.Bt + (size_t)z * 393216 + (size_t)(n0 + sr) * K + sh;
  for (int k0 = 0; k0 < K; k0 += 32) {
    s16x8 a0 = *(const s16x8*)(ga + k0);
    s16x8 a1 = *(const s16x8*)(ga + k0 + 8);
    s16x8 b0 = *(const s16x8*)(gb + k0);
    s16x8 b1 = *(const s16x8*)(gb + k0 + 8);
    __syncthreads();
    *(s16x8*)&As[sr][sh] = a0;
    *(s16x8*)&As[sr][sh + 8] = a1;
    *(s16x8*)&Bs[sr][sh] = b0;
    *(s16x8*)&Bs[sr][sh + 8] = b1;
    __syncthreads();
    s16x8 af[4], bfr[4];
#pragma unroll
    for (int mt = 0; mt < 4; mt++) af[mt] = *(const s16x8*)&As[wm * 64 + mt * 16 + lr][lg * 8];
#pragma unroll
    for (int nt = 0; nt < 4; nt++) bfr[nt] = *(const s16x8*)&Bs[wn * 64 + nt * 16 + lr][lg * 8];
#pragma unroll
    for (int mt = 0; mt < 4; mt++)
#pragma unroll
      for (int nt = 0; nt < 4; nt++) acc[mt][nt] = MFMA(af[mt], bfr[nt], acc[mt][nt]);
  }
  const int seg = n0 >> 9;
  if (seg == 2) {
    u16* vz = g.v + (size_t)z * 2097152;
#pragma unroll
    for (int mt = 0; mt < 4; mt++) {
      int nbase = m0 + wm * 64 + mt * 16 + lg * 4;
      int b = nbase >> 11, n = nbase & 2047;
#pragma unroll
      for (int nt = 0; nt < 4; nt++) {
        int col = n0 + wn * 64 + nt * 16 + lr;
        int hh = (col >> 6) & 7, d = col & 63;
        u16x4 w;
#pragma unroll
        for (int r = 0; r < 4; r++) w[r] = f2bf(acc[mt][nt][r]);
        *(u16x4*)(vz + (size_t)((b << 3) + hh) * 131072 + (size_t)d * 2048 + n) = w;
      }
    }
  } else {
    u16* dst = (seg == 0 ? g.q : g.k) + (size_t)z * 2097152;
    const float scv = (seg == 0) ? 0.125f : 1.0f;
#pragma unroll
    for (int mt = 0; mt < 4; mt++)
#pragma unroll
      for (int nt = 0; nt < 4; nt++)
#pragma unroll
        for (int r = 0; r < 4; r++) {
          int row = m0 + wm * 64 + mt * 16 + lg * 4 + r;
          int col = n0 + wn * 64 + nt * 16 + lr;
          int hh = (col >> 6) & 7, d = col & 63;
          int b = row >> 11, n = row & 2047;
          dst[(size_t)((b << 3) + hh) * 131072 + (size_t)n * 64 + d] = f2bf(acc[mt][nt][r] * scv);
        }
  }
}

// ---------------------------------------------------------------- WO GEMM 64x64 tile (+bias+residual->fp32)
struct Gemm64Args {
  const u16* A;   // [4096][512]
  const u16* Bt;  // [256][512]
  const float* bias[3];
  const float* res[3];
  float* outf;
  int aStr, btStr, outStr;  // per-branch strides (0 in serial mode)
};
__global__ __launch_bounds__(256) void gemm64_kernel(Gemm64Args g) {
  __shared__ u16 As[64][40];
  __shared__ u16 Bs[64][40];
  const int tid = threadIdx.x;
  const int lane = tid & 63, wid = tid >> 6;
  const int wm = wid >> 1, wn = wid & 1;
  const int lr = lane & 15, lg = lane >> 4;
  const int m0 = blockIdx.y * 64, n0 = blockIdx.x * 64;
  const int z = blockIdx.z;
  const int K = 512;
  f32x4 acc[2][2] = {};
  const int sr = tid >> 2, sh8 = (tid & 3) << 3;
  const u16* ga = g.A + (size_t)z * g.aStr + (size_t)(m0 + sr) * K + sh8;
  const u16* gb = g.Bt + (size_t)z * g.btStr + (size_t)(n0 + sr) * K + sh8;
  for (int k0 = 0; k0 < K; k0 += 32) {
    s16x8 a0 = *(const s16x8*)(ga + k0);
    s16x8 b0 = *(const s16x8*)(gb + k0);
    __syncthreads();
    *(s16x8*)&As[sr][sh8] = a0;
    *(s16x8*)&Bs[sr][sh8] = b0;
    __syncthreads();
    s16x8 af[2], bfr[2];
#pragma unroll
    for (int mt = 0; mt < 2; mt++) af[mt] = *(const s16x8*)&As[wm * 32 + mt * 16 + lr][lg * 8];
#pragma unroll
    for (int nt = 0; nt < 2; nt++) bfr[nt] = *(const s16x8*)&Bs[wn * 32 + nt * 16 + lr][lg * 8];
#pragma unroll
    for (int mt = 0; mt < 2; mt++)
#pragma unroll
      for (int nt = 0; nt < 2; nt++) acc[mt][nt] = MFMA(af[mt], bfr[nt], acc[mt][nt]);
  }
  float* of = g.outf + (size_t)z * g.outStr;
#pragma unroll
  for (int mt = 0; mt < 2; mt++)
#pragma unroll
    for (int nt = 0; nt < 2; nt++)
#pragma unroll
      for (int r = 0; r < 4; r++) {
        int row = m0 + wm * 32 + mt * 16 + lg * 4 + r;
        int col = n0 + wn * 32 + nt * 16 + lr;
        float val = acc[mt][nt][r] + g.bias[z][col] + g.res[z][(size_t)row * 256 + col];
        of[(size_t)row * 256 + col] = val;
      }
}

// ---------------------------------------------------------------- MLP GEMM, 128x64 tile, single bf16 term
struct GemmMlpArgs {
  const u16 *A, *Bt;
  int K;
  const float* bias;
  u16* oh;      // EPI 0
  float* outf;  // EPI 1
};
template <int EPI>
__global__ __launch_bounds__(256) void gemmmlp_kernel(GemmMlpArgs g) {
  __shared__ u16 As[128][40], Bs[64][40];
  const int tid = threadIdx.x;
  const int lane = tid & 63, wid = tid >> 6;
  const int wm = wid >> 1, wn = wid & 1;
  const int lr = lane & 15, lg = lane >> 4;
  const int m0 = blockIdx.y * 128, n0 = blockIdx.x * 64;
  const int K = g.K;
  f32x4 acc[4][2] = {};
  const int sra = tid >> 1, sha = (tid & 1) << 4;
  const int srb = tid >> 2, shb = (tid & 3) << 3;
  const u16* ga = g.A + (size_t)(m0 + sra) * K + sha;
  const u16* gb = g.Bt + (size_t)(n0 + srb) * K + shb;
  for (int k0 = 0; k0 < K; k0 += 32) {
    s16x8 a0 = *(const s16x8*)(ga + k0);
    s16x8 a1 = *(const s16x8*)(ga + k0 + 8);
    s16x8 b0 = *(const s16x8*)(gb + k0);
    __syncthreads();
    *(s16x8*)&As[sra][sha] = a0;
    *(s16x8*)&As[sra][sha + 8] = a1;
    *(s16x8*)&Bs[srb][shb] = b0;
    __syncthreads();
    s16x8 af[4], bfr[2];
#pragma unroll
    for (int mt = 0; mt < 4; mt++) af[mt] = *(const s16x8*)&As[wm * 64 + mt * 16 + lr][lg * 8];
#pragma unroll
    for (int nt = 0; nt < 2; nt++) bfr[nt] = *(const s16x8*)&Bs[wn * 32 + nt * 16 + lr][lg * 8];
#pragma unroll
    for (int mt = 0; mt < 4; mt++)
#pragma unroll
      for (int nt = 0; nt < 2; nt++) acc[mt][nt] = MFMA(af[mt], bfr[nt], acc[mt][nt]);
  }
#pragma unroll
  for (int mt = 0; mt < 4; mt++)
#pragma unroll
    for (int nt = 0; nt < 2; nt++)
#pragma unroll
      for (int r = 0; r < 4; r++) {
        int row = m0 + wm * 64 + mt * 16 + lg * 4 + r;
        int col = n0 + wn * 32 + nt * 16 + lr;
        float val = acc[mt][nt][r] + g.bias[col];
        if (EPI == 0) {
          float ge = 0.5f * val * (1.0f + erff(val * 0.70710678118654752f));
          g.oh[(size_t)row * 1024 + col] = f2bf(ge);
        } else {
          int chunk = col >> 8, cc = col & 255;
          float* p = g.outf + (size_t)chunk * 1048576 + (size_t)row * 256 + cc;
          *p = val + *p;
        }
      }
}

// ---------------------------------------------------------------- ReLU attention (R8-proven math)
// QBLK=128 (4 waves x 32 q), NSPLIT KV-splits of 32/NSPLIT tiles. V pre-transposed [bh][d][n].
// blockIdx.z = branch*NSPLIT + sp; serial mode: grid z=NSPLIT, strides 0.
template <int NSPLIT>
__global__ __launch_bounds__(256) void attn_kernel(const u16* q, const u16* k, const u16* vT,
                                                   u16* ao4, int brQkv, int brAo) {
  __shared__ u16 Ks[64][72];   // [kv][d]
  __shared__ u16 Vt[64][72];   // [d][kv]
  __shared__ u16 Ps[128][72];  // [q][kv]
  const int tid = threadIdx.x;
  const int lane = tid & 63, wid = tid >> 6;
  const int lr = lane & 15, lg = lane >> 4;
  const int qb = blockIdx.x, bh = blockIdx.y;
  const int br = blockIdx.z / NSPLIT, sp = blockIdx.z % NSPLIT;
  const size_t boff = (size_t)br * brQkv + (size_t)bh * 131072;
  const u16* qp = q + boff;
  const u16* kp = k + boff;
  const u16* vp = vT + boff;
  s16x8 qf[2][2];
#pragma unroll
  for (int mt = 0; mt < 2; mt++)
#pragma unroll
    for (int ks = 0; ks < 2; ks++)
      qf[mt][ks] = *(const s16x8*)(qp + (size_t)(qb * 128 + wid * 32 + mt * 16 + lr) * 64 + ks * 32 + lg * 8);
  f32x4 oacc[2][4] = {};
  const int sr = tid >> 2, sc = (tid & 3) << 4;
  const u16* kg = kp + sr * 64 + sc;    // K rows [kv][d]
  const u16* vg = vp + sr * 2048 + sc;  // vT rows [d][n]
  const int TPS = 32 / NSPLIT;
  const int ktL = sp * TPS, ktH = ktL + TPS;
  s16x8 kv0 = *(const s16x8*)(kg + ktL * 4096);
  s16x8 kv1 = *(const s16x8*)(kg + ktL * 4096 + 8);
  s16x8 vv0 = *(const s16x8*)(vg + ktL * 64);
  s16x8 vv1 = *(const s16x8*)(vg + ktL * 64 + 8);
  for (int kt = ktL; kt < ktH; kt++) {
    __syncthreads();
    *(s16x8*)&Ks[sr][sc] = kv0;
    *(s16x8*)&Ks[sr][sc + 8] = kv1;
    *(s16x8*)&Vt[sr][sc] = vv0;
    *(s16x8*)&Vt[sr][sc + 8] = vv1;
    __syncthreads();
    const int nx = (kt + 1 < ktH) ? kt + 1 : kt;
    kv0 = *(const s16x8*)(kg + nx * 4096);
    kv1 = *(const s16x8*)(kg + nx * 4096 + 8);
    vv0 = *(const s16x8*)(vg + nx * 64);
    vv1 = *(const s16x8*)(vg + nx * 64 + 8);
    f32x4 sacc[2][4] = {};
#pragma unroll
    for (int nt = 0; nt < 4; nt++)
#pragma unroll
      for (int ks = 0; ks < 2; ks++) {
        s16x8 kf = *(const s16x8*)&Ks[nt * 16 + lr][ks * 32 + lg * 8];
        sacc[0][nt] = MFMA(qf[0][ks], kf, sacc[0][nt]);
        sacc[1][nt] = MFMA(qf[1][ks], kf, sacc[1][nt]);
      }
#pragma unroll
    for (int mt = 0; mt < 2; mt++)
#pragma unroll
      for (int nt = 0; nt < 4; nt++)
#pragma unroll
        for (int r = 0; r < 4; r++) {
          float s = sacc[mt][nt][r];
          Ps[wid * 32 + mt * 16 + lg * 4 + r][nt * 16 + lr] = f2bf(s > 0.f ? s : 0.f);
        }
    __syncthreads();
#pragma unroll
    for (int ks = 0; ks < 2; ks++) {
      s16x8 pa0 = *(const s16x8*)&Ps[wid * 32 + lr][ks * 32 + lg * 8];
      s16x8 pa1 = *(const s16x8*)&Ps[wid * 32 + 16 + lr][ks * 32 + lg * 8];
#pragma unroll
      for (int nt = 0; nt < 4; nt++) {
        s16x8 vf = *(const s16x8*)&Vt[nt * 16 + lr][ks * 32 + lg * 8];
        oacc[0][nt] = MFMA(pa0, vf, oacc[0][nt]);
        oacc[1][nt] = MFMA(pa1, vf, oacc[1][nt]);
      }
    }
  }
  u16* aop = ao4 + (size_t)br * brAo + (size_t)sp * 2097152;
  const int b = bh >> 3, h = bh & 7;
#pragma unroll
  for (int mt = 0; mt < 2; mt++)
#pragma unroll
    for (int nt = 0; nt < 4; nt++)
#pragma unroll
      for (int r = 0; r < 4; r++) {
        int qrow = qb * 128 + wid * 32 + mt * 16 + lg * 4 + r;
        aop[(size_t)(b * 2048 + qrow) * 512 + h * 64 + nt * 16 + lr] = f2bf(oacc[mt][nt][r]);
      }
}

// ----------------------------------------------------------------
extern "C" void kernel_launch(void* const* d_in, const int* in_sizes, int n_in,
                              void* d_out, int out_size, void* d_ws, size_t ws_size,
                              hipStream_t stream) {
  const float* X[3] = {(const float*)d_in[0], (const float*)d_in[1], (const float*)d_in[2]};
  const float* G1[3] = {(const float*)d_in[3], (const float*)d_in[9], (const float*)d_in[15]};
  const float* B1[3] = {(const float*)d_in[4], (const float*)d_in[10], (const float*)d_in[16]};
  const float* WQKV[3] = {(const float*)d_in[5], (const float*)d_in[11], (const float*)d_in[17]};
  const float* RMS[3] = {(const float*)d_in[6], (const float*)d_in[12], (const float*)d_in[18]};
  const float* WO[3] = {(const float*)d_in[7], (const float*)d_in[13], (const float*)d_in[19]};
  const float* BO[3] = {(const float*)d_in[8], (const float*)d_in[14], (const float*)d_in[20]};
  const float* G2 = (const float*)d_in[21];
  const float* B2 = (const float*)d_in[22];
  const float* WFC1 = (const float*)d_in[23];
  const float* BFC1 = (const float*)d_in[24];
  const float* WFC2 = (const float*)d_in[25];
  const float* BFC2 = (const float*)d_in[26];
  float* dout = (float*)d_out;
  u16* W = (u16*)d_ws;

  const bool batched = ws_size >= 88080384ULL;  // 44,040,192 u16 elems

  // 1) all weight transposes, one launch (shared)
  u16* wqkvT = W;            // [3][1536][256]
  u16* woT = W + 1179648;    // [3][256][512]
  u16* fc1T = W + 1572864;   // [1024][768]
  u16* fc2T = W + 2359296;   // [768][1024]
  u16* xn = W + 3145728;     // [3][4096][256]   .. 6,291,456
  TrArgs ta;
  const float* srcs[8] = {WQKV[0], WQKV[1], WQKV[2], WO[0], WO[1], WO[2], WFC1, WFC2};
  u16* dsts[8] = {wqkvT, wqkvT + 393216, wqkvT + 786432, woT, woT + 131072, woT + 262144, fc1T, fc2T};
  int Ks_[8] = {256, 256, 256, 512, 512, 512, 768, 1024};
  int Ns_[8] = {1536, 1536, 1536, 256, 256, 256, 1024, 768};
  int tst[9] = {0, 384, 768, 1152, 1280, 1408, 1536, 2304, 3072};
  for (int i = 0; i < 8; i++) {
    ta.src[i] = srcs[i];
    ta.dst[i] = dsts[i];
    ta.K[i] = Ks_[i];
    ta.N[i] = Ns_[i];
    ta.tstart[i] = tst[i];
  }
  ta.tstart[8] = tst[8];
  hipLaunchKernelGGL(tr_kernel, dim3(3072), dim3(256), 0, stream, ta);

  // 2) LN1 (shared)
  LN1Args la;
  for (int i = 0; i < 3; i++) {
    la.x[i] = X[i];
    la.g[i] = G1[i];
    la.b[i] = B1[i];
  }
  la.out = xn;
  hipLaunchKernelGGL(ln1_kernel, dim3(1024, 3), dim3(256), 0, stream, la);

  u16 *ln2b, *hbuf;

  if (batched) {
    // Batched layout: qall 6,291,456..12,582,912; kall ..18,874,368; vall ..25,165,824;
    // ao4 [3][2][4096][512] ..37,748,736; aoN [3][4096][512] ..44,040,192.
    u16* qall = W + 6291456;
    u16* kall = W + 12582912;
    u16* vall = W + 18874368;
    u16* ao4 = W + 25165824;
    u16* aoN = W + 37748736;
    ln2b = W + 6291456;   // overlays qall (dead in stage B)
    hbuf = W + 9437184;

    GemmQkvArgs gq = {xn, wqkvT, qall, kall, vall};
    hipLaunchKernelGGL(gemmqkv_kernel, dim3(12, 32, 3), dim3(256), 0, stream, gq);

    hipLaunchKernelGGL(attn_kernel<2>, dim3(16, 16, 6), dim3(256), 0, stream,
                       qall, kall, vall, ao4, 2097152, 4194304);

    RmsArgs ra;
    ra.ao4 = ao4;
    for (int i = 0; i < 3; i++) ra.sc[i] = RMS[i];
    ra.aoN = aoN;
    ra.brAo = 4194304;
    ra.brAoN = 2097152;
    hipLaunchKernelGGL(rms_sum_kernel<2>, dim3(1024, 3), dim3(256), 0, stream, ra);

    Gemm64Args gw;
    gw.A = aoN;
    gw.Bt = woT;
    for (int i = 0; i < 3; i++) {
      gw.bias[i] = BO[i];
      gw.res[i] = X[i];
    }
    gw.outf = dout;
    gw.aStr = 2097152;
    gw.btStr = 131072;
    gw.outStr = 1048576;
    hipLaunchKernelGGL(gemm64_kernel, dim3(4, 64, 3), dim3(256), 0, stream, gw);
  } else {
    // Serial fallback (R8-proven, peak 44 MiB)
    u16* qz = W + 6291456;
    u16* kz = W + 8388608;
    u16* vz = W + 10485760;
    u16* ao4 = W + 12582912;  // [4][4096][512]
    u16* aoN = W + 20971520;
    ln2b = W + 6291456;
    hbuf = W + 9437184;

    for (int z = 0; z < 3; z++) {
      GemmQkvArgs gq = {xn + (size_t)z * 1048576, wqkvT + (size_t)z * 393216, qz, kz, vz};
      hipLaunchKernelGGL(gemmqkv_kernel, dim3(12, 32, 1), dim3(256), 0, stream, gq);

      hipLaunchKernelGGL(attn_kernel<4>, dim3(16, 16, 4), dim3(256), 0, stream,
                         qz, kz, vz, ao4, 0, 0);

      RmsArgs ra;
      ra.ao4 = ao4;
      ra.sc[0] = RMS[z];
      ra.sc[1] = RMS[z];
      ra.sc[2] = RMS[z];
      ra.aoN = aoN;
      ra.brAo = 0;
      ra.brAoN = 0;
      hipLaunchKernelGGL(rms_sum_kernel<4>, dim3(1024, 1), dim3(256), 0, stream, ra);

      Gemm64Args gw;
      gw.A = aoN;
      gw.Bt = woT + (size_t)z * 131072;
      for (int i = 0; i < 3; i++) {
        gw.bias[i] = BO[z];
        gw.res[i] = X[z];
      }
      gw.outf = dout + (size_t)z * 1048576;
      gw.aStr = 0;
      gw.btStr = 0;
      gw.outStr = 0;
      hipLaunchKernelGGL(gemm64_kernel, dim3(4, 64, 1), dim3(256), 0, stream, gw);
    }
  }

  // 4) LN2 -> bf16
  hipLaunchKernelGGL(ln2_kernel, dim3(1024), dim3(256), 0, stream, dout, G2, B2, ln2b);

  // 5) FC1 (M=4096,N=1024,K=768) + gelu -> hbuf
  GemmMlpArgs g1 = {};
  g1.A = ln2b;
  g1.Bt = fc1T;
  g1.K = 768;
  g1.bias = BFC1;
  g1.oh = hbuf;
  hipLaunchKernelGGL(gemmmlp_kernel<0>, dim3(16, 32), dim3(256), 0, stream, g1);

  // 6) FC2 (M=4096,N=768,K=1024) + bias + residual RMW on d_out
  GemmMlpArgs g2 = {};
  g2.A = hbuf;
  g2.Bt = fc2T;
  g2.K = 1024;
  g2.bias = BFC2;
  g2.outf = dout;
  hipLaunchKernelGGL(gemmmlp_kernel<1>, dim3(12, 32), dim3(256), 0, stream, g2);
}